// Round 10
// baseline (343.259 us; speedup 1.0000x reference)
//
#include <hip/hip_runtime.h>
#include <hip/hip_bf16.h>

typedef unsigned short u16;
typedef float  f32x4  __attribute__((ext_vector_type(4)));
typedef float  f32x16 __attribute__((ext_vector_type(16)));
typedef __bf16 bf16x8 __attribute__((ext_vector_type(8)));
typedef unsigned short u16x8 __attribute__((ext_vector_type(8)));
typedef unsigned short u16x4 __attribute__((ext_vector_type(4)));

__device__ __forceinline__ u16 f2bfu(float f) {
    __hip_bfloat16 h = __float2bfloat16(f);
    return __builtin_bit_cast(unsigned short, h);
}

constexpr int kHW = 196;   // 14*14
constexpr int kKC = 25;    // ceil(196/8) k-chunks
constexpr int kLC = 25;    // ceil(196/8) l-chunks

// ---------------- prep: interleave weights [k>>3][n][k8] bf16 + zero out ----------
// Layout serves BOTH 16x16 (kk=k>>5,kg=(k>>3)&3) and 32x32 (kk16=k>>4,hi=(k>>3)&1)
// fragment addressing since (kk<<2)+kg == (kk16<<1)+hi == k>>3.
__global__ __launch_bounds__(256)
void k_prep(const float* __restrict__ pw, u16* __restrict__ pwi,
            const float* __restrict__ w1, u16* __restrict__ w1li, u16* __restrict__ w1ki,
            const float* __restrict__ w2, u16* __restrict__ w2i,
            const float* __restrict__ w3, u16* __restrict__ w3i,
            float* __restrict__ out) {
    int id = blockIdx.x;
    int n = threadIdx.x;
    if (id < 512) {
        int k = id;
        pwi[((k >> 3) << 11) + (n << 3) + (k & 7)] = f2bfu(pw[n * 512 + k]);
    } else if (id < 1536) {
        int k = (id - 512) & 255;
        int idx = ((k >> 3) << 11) + (n << 3) + (k & 7);
        if (id < 768)       w1li[idx] = f2bfu(w1[k * 256 + n]);
        else if (id < 1024) w1ki[idx] = f2bfu(w1[(k + 256) * 256 + n]);
        else if (id < 1280) w2i[idx]  = f2bfu(w2[k * 256 + n]);
        else                w3i[idx]  = f2bfu(w3[k * 256 + n]);
    } else {
        out[(id - 1536) * 256 + n] = 0.f;  // zero for atomic accumulation
    }
}

// ---------------- MFMA prologue: xf then al/ak. grid (14, 8), 256 thr ----------------
__global__ __launch_bounds__(256, 2)
void k_xa3(const float* __restrict__ im, const u16* __restrict__ pwi,
           const float* __restrict__ pb, const u16* __restrict__ w1li,
           const u16* __restrict__ w1ki, float* __restrict__ al,
           float* __restrict__ ak) {
    __shared__ u16 imT[16 * 512];   // [p][i] bf16, swizzled rows (1KB), 16KB
    __shared__ u16 xfs[16 * 256];   // [p][c] bf16, swizzled rows (512B), 8KB
    const int tid = threadIdx.x;
    const int b = blockIdx.y;
    const int p0 = blockIdx.x * 14;

    {
        int t4 = tid & 3;
        int ibase = tid >> 2;
#pragma unroll
        for (int it = 0; it < 8; ++it) {
            int i = it * 64 + ibase;
            const float* src = im + (b * 512 + i) * kHW;
#pragma unroll
            for (int j = 0; j < 4; ++j) {
                int prow = t4 * 4 + j;
                int p = p0 + prow; if (p > 195) p = 195;
                int byte = (prow << 10) + (i << 1);
                byte ^= (prow & 7) << 4;
                *(u16*)((char*)imT + byte) = f2bfu(src[p]);
            }
        }
    }
    __syncthreads();

    const int lane = tid & 63;
    const int wn = tid >> 6;
    const int l15 = lane & 15;
    const int kg = lane >> 4;
    const int wbase = (wn * 64 + l15) << 3;

    f32x4 acc[4];
#pragma unroll
    for (int fn = 0; fn < 4; ++fn) acc[fn] = f32x4{0.f, 0.f, 0.f, 0.f};
    for (int kk = 0; kk < 16; ++kk) {
        int kb = kk * 32 + kg * 8;
        int byte = (l15 << 10) + (kb << 1);
        byte ^= (l15 & 7) << 4;
        bf16x8 hb = __builtin_bit_cast(bf16x8, *(const u16x8*)((const char*)imT + byte));
        const u16* wp = pwi + ((((kk << 2) + kg) << 11) + wbase);
#pragma unroll
        for (int fn = 0; fn < 4; ++fn) {
            bf16x8 aw = __builtin_bit_cast(bf16x8, *(const u16x8*)(wp + (fn << 7)));
            acc[fn] = __builtin_amdgcn_mfma_f32_16x16x32_bf16(aw, hb, acc[fn], 0, 0, 0);
        }
    }
#pragma unroll
    for (int fn = 0; fn < 4; ++fn) {
        f32x4 pbv = *(const f32x4*)(pb + wn * 64 + fn * 16 + kg * 4);
        u16x4 pv;
#pragma unroll
        for (int r = 0; r < 4; ++r) pv[r] = f2bfu(acc[fn][r] + pbv[r]);
        int byte = (l15 << 9) + ((wn * 64 + fn * 16 + kg * 4) << 1);
        byte ^= (l15 & 7) << 4;
        *(u16x4*)((char*)xfs + byte) = pv;
    }
    __syncthreads();

    const int p = p0 + l15;
    const bool valid = (l15 < 14) && (p < kHW);
#pragma unroll
    for (int sel = 0; sel < 2; ++sel) {
        const u16* wsrc = sel ? w1ki : w1li;
        f32x4 a2[4];
#pragma unroll
        for (int fn = 0; fn < 4; ++fn) a2[fn] = f32x4{0.f, 0.f, 0.f, 0.f};
        for (int kk = 0; kk < 8; ++kk) {
            int kb = kk * 32 + kg * 8;
            int byte = (l15 << 9) + (kb << 1);
            byte ^= (l15 & 7) << 4;
            bf16x8 hb = __builtin_bit_cast(bf16x8, *(const u16x8*)((const char*)xfs + byte));
            const u16* wp = wsrc + ((((kk << 2) + kg) << 11) + wbase);
#pragma unroll
            for (int fn = 0; fn < 4; ++fn) {
                bf16x8 aw = __builtin_bit_cast(bf16x8, *(const u16x8*)(wp + (fn << 7)));
                a2[fn] = __builtin_amdgcn_mfma_f32_16x16x32_bf16(aw, hb, a2[fn], 0, 0, 0);
            }
        }
        if (valid) {
            float* dst = (sel ? ak : al) + ((b * kHW + p) << 8) + wn * 64 + kg * 4;
#pragma unroll
            for (int fn = 0; fn < 4; ++fn) *(f32x4*)(dst + fn * 16) = a2[fn];
        }
    }
}

// ---------------- main v8: 32x32x16 MFMA, setprio, fused atomic reduce ------------
// grid (25 lc, 25 kc, 8 b), block 256 = 4 waves (wn = ch quarter, 64 ch).
// Wave tile: 64 ch x 64 pairs = 2x2 tiles of 32x32 -> acc[2][2] f32x16 = 64 AGPR.
// C/D layout (m74/m101): col = lane&31 (pair), row = (r&3) + 8*(r>>2) + 4*(lane>>5).
__global__ __launch_bounds__(256, 3)
void k_main8(const float* __restrict__ ak, const float* __restrict__ al,
             const float* __restrict__ b1, const u16* __restrict__ w2i,
             const float* __restrict__ b2, const u16* __restrict__ w3i,
             const float* __restrict__ b3, float* __restrict__ out) {
    __shared__ u16 smem[64 * 256];   // 32 KB: h1, then h2 in-place
    __shared__ float raw[16 * 256];  // 16 KB: 8 ak rows then 8 al rows (fp32)
    const int tid = threadIdx.x;
    const int lc = blockIdx.x, kc = blockIdx.y, b = blockIdx.z;
    const int k0 = kc * 8, l0 = lc * 8;

    // ---- raw stage: 16 source rows global -> LDS ----
    {
        int r = tid >> 4, t = tid & 15;
        int src_row = (r < 8) ? (k0 + r) : (l0 + (r - 8));
        if (src_row > 195) src_row = 195;
        const float* src = ((r < 8) ? ak : al) + ((b * kHW + src_row) << 8);
#pragma unroll
        for (int j = 0; j < 4; ++j)
            *(f32x4*)&raw[r * 256 + j * 64 + t * 4] = *(const f32x4*)(src + j * 64 + t * 4);
    }
    __syncthreads();

    // ---- build h1 -> bf16 LDS [pair][ch], swizzle ^((row&15)<<4) ----
    {
        const int cc = tid & 31;
        f32x4 c0v = *(const f32x4*)(b1 + (cc << 3));
        f32x4 c1v = *(const f32x4*)(b1 + (cc << 3) + 4);
#pragma unroll
        for (int it = 0; it < 8; ++it) {
            int row = (it * 256 + tid) >> 5;
            const float* akp = &raw[(row >> 3) * 256 + (cc << 3)];
            const float* alp = &raw[(8 + (row & 7)) * 256 + (cc << 3)];
            f32x4 k0v = *(const f32x4*)akp;
            f32x4 k1v = *(const f32x4*)(akp + 4);
            f32x4 l0v = *(const f32x4*)alp;
            f32x4 l1v = *(const f32x4*)(alp + 4);
            u16x8 v;
#pragma unroll
            for (int j = 0; j < 4; ++j) {
                v[j]     = f2bfu(fmaxf(k0v[j] + l0v[j] + c0v[j], 0.f));
                v[4 + j] = f2bfu(fmaxf(k1v[j] + l1v[j] + c1v[j], 0.f));
            }
            int byte = (row << 9) + (cc << 4);
            byte ^= (row & 15) << 4;
            *(u16x8*)((char*)smem + byte) = v;
        }
    }
    __syncthreads();

    const int lane = tid & 63;
    const int wn = tid >> 6;   // ch quarter 0..3
    const int l31 = lane & 31;
    const int hi = lane >> 5;  // K-half
    const int wbase = (wn * 64 + l31) << 3;

    f32x16 acc[2][2];  // [a32 ch-tile][b32 pair-tile]

    // ---- GEMM1: h2^T = w2 x h1^T (K=256, 16 steps of K=16) ----
#pragma unroll
    for (int a = 0; a < 2; ++a)
#pragma unroll
        for (int c = 0; c < 2; ++c)
#pragma unroll
            for (int r = 0; r < 16; ++r) acc[a][c][r] = 0.f;
    __builtin_amdgcn_s_setprio(1);
    for (int kk = 0; kk < 16; ++kk) {
        int kbyte = kk * 32 + hi * 16;
        bf16x8 hb[2];
#pragma unroll
        for (int b32 = 0; b32 < 2; ++b32) {
            int prow = b32 * 32 + l31;
            int byte = (prow << 9) + kbyte;
            byte ^= (prow & 15) << 4;
            hb[b32] = __builtin_bit_cast(bf16x8, *(const u16x8*)((const char*)smem + byte));
        }
        const u16* wp = w2i + (((kk << 1) + hi) << 11) + wbase;
#pragma unroll
        for (int a32 = 0; a32 < 2; ++a32) {
            bf16x8 aw = __builtin_bit_cast(bf16x8, *(const u16x8*)(wp + (a32 << 8)));
#pragma unroll
            for (int b32 = 0; b32 < 2; ++b32)
                acc[a32][b32] = __builtin_amdgcn_mfma_f32_32x32x16_bf16(
                    aw, hb[b32], acc[a32][b32], 0, 0, 0);
        }
    }
    __builtin_amdgcn_s_setprio(0);
    __syncthreads();

    // ---- epilogue: h2 = relu(D1 + b2) -> bf16 LDS, packed 8B writes ----
#pragma unroll
    for (int a32 = 0; a32 < 2; ++a32) {
#pragma unroll
        for (int g = 0; g < 4; ++g) {
            int ch = wn * 64 + a32 * 32 + hi * 4 + g * 8;
            f32x4 b2v = *(const f32x4*)(b2 + ch);
#pragma unroll
            for (int b32 = 0; b32 < 2; ++b32) {
                int pair = b32 * 32 + l31;
                u16x4 pv;
#pragma unroll
                for (int m = 0; m < 4; ++m)
                    pv[m] = f2bfu(fmaxf(acc[a32][b32][g * 4 + m] + b2v[m], 0.f));
                int byte = (pair << 9) + (ch << 1);
                byte ^= (pair & 15) << 4;
                *(u16x4*)((char*)smem + byte) = pv;
            }
        }
    }
    __syncthreads();

    // ---- GEMM2: h3^T = w3 x h2^T ----
#pragma unroll
    for (int a = 0; a < 2; ++a)
#pragma unroll
        for (int c = 0; c < 2; ++c)
#pragma unroll
            for (int r = 0; r < 16; ++r) acc[a][c][r] = 0.f;
    __builtin_amdgcn_s_setprio(1);
    for (int kk = 0; kk < 16; ++kk) {
        int kbyte = kk * 32 + hi * 16;
        bf16x8 hb[2];
#pragma unroll
        for (int b32 = 0; b32 < 2; ++b32) {
            int prow = b32 * 32 + l31;
            int byte = (prow << 9) + kbyte;
            byte ^= (prow & 15) << 4;
            hb[b32] = __builtin_bit_cast(bf16x8, *(const u16x8*)((const char*)smem + byte));
        }
        const u16* wp = w3i + (((kk << 1) + hi) << 11) + wbase;
#pragma unroll
        for (int a32 = 0; a32 < 2; ++a32) {
            bf16x8 aw = __builtin_bit_cast(bf16x8, *(const u16x8*)(wp + (a32 << 8)));
#pragma unroll
            for (int b32 = 0; b32 < 2; ++b32)
                acc[a32][b32] = __builtin_amdgcn_mfma_f32_32x32x16_bf16(
                    aw, hb[b32], acc[a32][b32], 0, 0, 0);
        }
    }
    __builtin_amdgcn_s_setprio(0);

    // ---- masked col-sum + 32-lane reduce + atomic accumulate to out ----
#pragma unroll
    for (int a32 = 0; a32 < 2; ++a32) {
        float s[4][4] = {};
#pragma unroll
        for (int b32 = 0; b32 < 2; ++b32) {
            int pr = b32 * 32 + l31;
            int ki = k0 + (pr >> 3);
            int li = l0 + (pr & 7);
            float vm = (ki < kHW && li < kHW) ? 1.f : 0.f;
#pragma unroll
            for (int g = 0; g < 4; ++g) {
                f32x4 b3v = *(const f32x4*)(b3 + wn * 64 + a32 * 32 + hi * 4 + g * 8);
#pragma unroll
                for (int m = 0; m < 4; ++m)
                    s[g][m] += vm * fmaxf(acc[a32][b32][g * 4 + m] + b3v[m], 0.f);
            }
        }
#pragma unroll
        for (int g = 0; g < 4; ++g)
#pragma unroll
            for (int m = 0; m < 4; ++m) {
                s[g][m] += __shfl_xor(s[g][m], 1);
                s[g][m] += __shfl_xor(s[g][m], 2);
                s[g][m] += __shfl_xor(s[g][m], 4);
                s[g][m] += __shfl_xor(s[g][m], 8);
                s[g][m] += __shfl_xor(s[g][m], 16);
            }
        if (l31 == 0) {
            float* op = out + (b << 8) + wn * 64 + a32 * 32 + hi * 4;
#pragma unroll
            for (int g = 0; g < 4; ++g)
#pragma unroll
                for (int m = 0; m < 4; ++m)
                    atomicAdd(op + g * 8 + m, s[g][m]);
        }
    }
}

extern "C" void kernel_launch(void* const* d_in, const int* in_sizes, int n_in,
                              void* d_out, int out_size, void* d_ws, size_t ws_size,
                              hipStream_t stream) {
    const float* im = (const float*)d_in[0];
    const float* pw = (const float*)d_in[3];
    const float* pb = (const float*)d_in[4];
    const float* w1 = (const float*)d_in[5];
    const float* b1 = (const float*)d_in[6];
    const float* w2 = (const float*)d_in[7];
    const float* b2 = (const float*)d_in[8];
    const float* w3 = (const float*)d_in[9];
    const float* b3 = (const float*)d_in[10];
    float* out = (float*)d_out;

    float* al  = (float*)d_ws;            // 8*196*256
    float* ak  = al + 8 * 196 * 256;
    u16* pwi  = (u16*)(ak + 8 * 196 * 256);  // [64 k8-blk][256 n][8 k]
    u16* w1li = pwi + 512 * 256;             // [32 k8-blk][256 n][8 k]
    u16* w1ki = w1li + 256 * 256;
    u16* w2i  = w1ki + 256 * 256;
    u16* w3i  = w2i + 256 * 256;

    hipLaunchKernelGGL(k_prep, dim3(1544), dim3(256), 0, stream,
                       pw, pwi, w1, w1li, w1ki, w2, w2i, w3, w3i, out);
    hipLaunchKernelGGL(k_xa3, dim3(14, 8), dim3(256), 0, stream,
                       im, pwi, pb, w1li, w1ki, al, ak);
    hipLaunchKernelGGL(k_main8, dim3(kLC, kKC, 8), dim3(256), 0, stream,
                       ak, al, b1, w2i, b2, w3i, b3, out);
}

// Round 11
// 214.891 us; speedup vs baseline: 1.5974x; 1.5974x over previous
//
#include <hip/hip_runtime.h>
#include <hip/hip_bf16.h>

typedef unsigned short u16;
typedef float  f32x4  __attribute__((ext_vector_type(4)));
typedef __bf16 bf16x8 __attribute__((ext_vector_type(8)));
typedef unsigned short u16x8 __attribute__((ext_vector_type(8)));
typedef unsigned short u16x4 __attribute__((ext_vector_type(4)));

__device__ __forceinline__ u16 f2bfu(float f) {
    __hip_bfloat16 h = __float2bfloat16(f);
    return __builtin_bit_cast(unsigned short, h);
}

constexpr int kHW = 196;   // 14*14
constexpr int kKC = 25;    // ceil(196/8) k-chunks
constexpr int kLC = 25;    // ceil(196/8) l-chunks

// ---------------- prep: interleave weights [k>>3][n][k8] bf16 + zero out ----------
__global__ __launch_bounds__(256)
void k_prep(const float* __restrict__ pw, u16* __restrict__ pwi,
            const float* __restrict__ w1, u16* __restrict__ w1li, u16* __restrict__ w1ki,
            const float* __restrict__ w2, u16* __restrict__ w2i,
            const float* __restrict__ w3, u16* __restrict__ w3i,
            float* __restrict__ out) {
    int id = blockIdx.x;
    int n = threadIdx.x;
    if (id < 512) {
        int k = id;
        pwi[((k >> 3) << 11) + (n << 3) + (k & 7)] = f2bfu(pw[n * 512 + k]);
    } else if (id < 1536) {
        int k = (id - 512) & 255;
        int idx = ((k >> 3) << 11) + (n << 3) + (k & 7);
        if (id < 768)       w1li[idx] = f2bfu(w1[k * 256 + n]);
        else if (id < 1024) w1ki[idx] = f2bfu(w1[(k + 256) * 256 + n]);
        else if (id < 1280) w2i[idx]  = f2bfu(w2[k * 256 + n]);
        else                w3i[idx]  = f2bfu(w3[k * 256 + n]);
    } else {
        out[(id - 1536) * 256 + n] = 0.f;  // zero for atomic accumulation
    }
}

// ---------------- MFMA prologue: xf then al/ak. grid (14, 8), 256 thr ----------------
__global__ __launch_bounds__(256, 2)
void k_xa3(const float* __restrict__ im, const u16* __restrict__ pwi,
           const float* __restrict__ pb, const u16* __restrict__ w1li,
           const u16* __restrict__ w1ki, float* __restrict__ al,
           float* __restrict__ ak) {
    __shared__ u16 imT[16 * 512];   // [p][i] bf16, swizzled rows (1KB), 16KB
    __shared__ u16 xfs[16 * 256];   // [p][c] bf16, swizzled rows (512B), 8KB
    const int tid = threadIdx.x;
    const int b = blockIdx.y;
    const int p0 = blockIdx.x * 14;

    {
        int t4 = tid & 3;
        int ibase = tid >> 2;
#pragma unroll
        for (int it = 0; it < 8; ++it) {
            int i = it * 64 + ibase;
            const float* src = im + (b * 512 + i) * kHW;
#pragma unroll
            for (int j = 0; j < 4; ++j) {
                int prow = t4 * 4 + j;
                int p = p0 + prow; if (p > 195) p = 195;
                int byte = (prow << 10) + (i << 1);
                byte ^= (prow & 7) << 4;
                *(u16*)((char*)imT + byte) = f2bfu(src[p]);
            }
        }
    }
    __syncthreads();

    const int lane = tid & 63;
    const int wn = tid >> 6;
    const int l15 = lane & 15;
    const int kg = lane >> 4;
    const int wbase = (wn * 64 + l15) << 3;

    f32x4 acc[4];
#pragma unroll
    for (int fn = 0; fn < 4; ++fn) acc[fn] = f32x4{0.f, 0.f, 0.f, 0.f};
    for (int kk = 0; kk < 16; ++kk) {
        int kb = kk * 32 + kg * 8;
        int byte = (l15 << 10) + (kb << 1);
        byte ^= (l15 & 7) << 4;
        bf16x8 hb = __builtin_bit_cast(bf16x8, *(const u16x8*)((const char*)imT + byte));
        const u16* wp = pwi + ((((kk << 2) + kg) << 11) + wbase);
#pragma unroll
        for (int fn = 0; fn < 4; ++fn) {
            bf16x8 aw = __builtin_bit_cast(bf16x8, *(const u16x8*)(wp + (fn << 7)));
            acc[fn] = __builtin_amdgcn_mfma_f32_16x16x32_bf16(aw, hb, acc[fn], 0, 0, 0);
        }
    }
#pragma unroll
    for (int fn = 0; fn < 4; ++fn) {
        f32x4 pbv = *(const f32x4*)(pb + wn * 64 + fn * 16 + kg * 4);
        u16x4 pv;
#pragma unroll
        for (int r = 0; r < 4; ++r) pv[r] = f2bfu(acc[fn][r] + pbv[r]);
        int byte = (l15 << 9) + ((wn * 64 + fn * 16 + kg * 4) << 1);
        byte ^= (l15 & 7) << 4;
        *(u16x4*)((char*)xfs + byte) = pv;
    }
    __syncthreads();

    const int p = p0 + l15;
    const bool valid = (l15 < 14) && (p < kHW);
#pragma unroll
    for (int sel = 0; sel < 2; ++sel) {
        const u16* wsrc = sel ? w1ki : w1li;
        f32x4 a2[4];
#pragma unroll
        for (int fn = 0; fn < 4; ++fn) a2[fn] = f32x4{0.f, 0.f, 0.f, 0.f};
        for (int kk = 0; kk < 8; ++kk) {
            int kb = kk * 32 + kg * 8;
            int byte = (l15 << 9) + (kb << 1);
            byte ^= (l15 & 7) << 4;
            bf16x8 hb = __builtin_bit_cast(bf16x8, *(const u16x8*)((const char*)xfs + byte));
            const u16* wp = wsrc + ((((kk << 2) + kg) << 11) + wbase);
#pragma unroll
            for (int fn = 0; fn < 4; ++fn) {
                bf16x8 aw = __builtin_bit_cast(bf16x8, *(const u16x8*)(wp + (fn << 7)));
                a2[fn] = __builtin_amdgcn_mfma_f32_16x16x32_bf16(aw, hb, a2[fn], 0, 0, 0);
            }
        }
        if (valid) {
            float* dst = (sel ? ak : al) + ((b * kHW + p) << 8) + wn * 64 + kg * 4;
#pragma unroll
            for (int fn = 0; fn < 4; ++fn) *(f32x4*)(dst + fn * 16) = a2[fn];
        }
    }
}

// ---------------- main fused pair kernel (R8-exact body + atomic out) ----------------
// grid (25 lc, 25 kc, 8 b), block 256 (4 waves; wave = ch quarter).
// Tile: (8 k x 8 l) = 64 pairs x 256 ch. LDS 48KB -> 3 blocks/CU.
__global__ __launch_bounds__(256, 3)
void k_main7(const float* __restrict__ ak, const float* __restrict__ al,
             const float* __restrict__ b1, const u16* __restrict__ w2i,
             const float* __restrict__ b2, const u16* __restrict__ w3i,
             const float* __restrict__ b3, float* __restrict__ out) {
    __shared__ u16 smem[64 * 256];   // 32 KB: h1, then h2 in-place
    __shared__ float raw[16 * 256];  // 16 KB: 8 ak rows then 8 al rows (fp32)
    const int tid = threadIdx.x;
    const int lc = blockIdx.x, kc = blockIdx.y, b = blockIdx.z;
    const int k0 = kc * 8, l0 = lc * 8;

    {
        int r = tid >> 4;
        int t = tid & 15;
        int src_row = (r < 8) ? (k0 + r) : (l0 + (r - 8));
        if (src_row > 195) src_row = 195;
        const float* src = ((r < 8) ? ak : al) + ((b * kHW + src_row) << 8);
#pragma unroll
        for (int j = 0; j < 4; ++j)
            *(f32x4*)&raw[r * 256 + j * 64 + t * 4] = *(const f32x4*)(src + j * 64 + t * 4);
    }
    __syncthreads();

    {
        const int cc = tid & 31;
        f32x4 c0v = *(const f32x4*)(b1 + (cc << 3));
        f32x4 c1v = *(const f32x4*)(b1 + (cc << 3) + 4);
#pragma unroll
        for (int it = 0; it < 8; ++it) {
            int row = (it * 256 + tid) >> 5;
            const float* akp = &raw[(row >> 3) * 256 + (cc << 3)];
            const float* alp = &raw[(8 + (row & 7)) * 256 + (cc << 3)];
            f32x4 k0v = *(const f32x4*)akp;
            f32x4 k1v = *(const f32x4*)(akp + 4);
            f32x4 l0v = *(const f32x4*)alp;
            f32x4 l1v = *(const f32x4*)(alp + 4);
            u16x8 v;
#pragma unroll
            for (int j = 0; j < 4; ++j) {
                v[j]     = f2bfu(fmaxf(k0v[j] + l0v[j] + c0v[j], 0.f));
                v[4 + j] = f2bfu(fmaxf(k1v[j] + l1v[j] + c1v[j], 0.f));
            }
            int byte = (row << 9) + (cc << 4);
            byte ^= (row & 7) << 4;
            *(u16x8*)((char*)smem + byte) = v;
        }
    }
    __syncthreads();

    const int lane = tid & 63;
    const int wn = tid >> 6;
    const int l15 = lane & 15;
    const int kg = lane >> 4;

    f32x4 acc[4][4];
    const int wbase = (wn * 64 + l15) << 3;

#pragma unroll
    for (int fn = 0; fn < 4; ++fn)
#pragma unroll
        for (int fm = 0; fm < 4; ++fm) acc[fn][fm] = f32x4{0.f, 0.f, 0.f, 0.f};
    for (int kk = 0; kk < 8; ++kk) {
        int kb = kk * 32 + kg * 8;
        bf16x8 hb[4];
#pragma unroll
        for (int fm = 0; fm < 4; ++fm) {
            int row = fm * 16 + l15;
            int byte = (row << 9) + (kb << 1);
            byte ^= (row & 7) << 4;
            hb[fm] = __builtin_bit_cast(bf16x8, *(const u16x8*)((const char*)smem + byte));
        }
        const u16* wp = w2i + ((((kk << 2) + kg) << 11) + wbase);
#pragma unroll
        for (int fn = 0; fn < 4; ++fn) {
            bf16x8 aw = __builtin_bit_cast(bf16x8, *(const u16x8*)(wp + (fn << 7)));
#pragma unroll
            for (int fm = 0; fm < 4; ++fm)
                acc[fn][fm] = __builtin_amdgcn_mfma_f32_16x16x32_bf16(aw, hb[fm], acc[fn][fm], 0, 0, 0);
        }
    }
    __syncthreads();

#pragma unroll
    for (int fn = 0; fn < 4; ++fn) {
        f32x4 b2v = *(const f32x4*)(b2 + wn * 64 + fn * 16 + kg * 4);
#pragma unroll
        for (int fm = 0; fm < 4; ++fm) {
            int prow = fm * 16 + l15;
            u16x4 pv;
#pragma unroll
            for (int r = 0; r < 4; ++r)
                pv[r] = f2bfu(fmaxf(acc[fn][fm][r] + b2v[r], 0.f));
            int byte = (prow << 9) + ((wn * 64 + fn * 16 + kg * 4) << 1);
            byte ^= (prow & 7) << 4;
            *(u16x4*)((char*)smem + byte) = pv;
        }
    }
    __syncthreads();

#pragma unroll
    for (int fn = 0; fn < 4; ++fn)
#pragma unroll
        for (int fm = 0; fm < 4; ++fm) acc[fn][fm] = f32x4{0.f, 0.f, 0.f, 0.f};
    for (int kk = 0; kk < 8; ++kk) {
        int kb = kk * 32 + kg * 8;
        bf16x8 hb[4];
#pragma unroll
        for (int fm = 0; fm < 4; ++fm) {
            int row = fm * 16 + l15;
            int byte = (row << 9) + (kb << 1);
            byte ^= (row & 7) << 4;
            hb[fm] = __builtin_bit_cast(bf16x8, *(const u16x8*)((const char*)smem + byte));
        }
        const u16* wp = w3i + ((((kk << 2) + kg) << 11) + wbase);
#pragma unroll
        for (int fn = 0; fn < 4; ++fn) {
            bf16x8 aw = __builtin_bit_cast(bf16x8, *(const u16x8*)(wp + (fn << 7)));
#pragma unroll
            for (int fm = 0; fm < 4; ++fm)
                acc[fn][fm] = __builtin_amdgcn_mfma_f32_16x16x32_bf16(aw, hb[fm], acc[fn][fm], 0, 0, 0);
        }
    }

    float s[4][4] = {};
#pragma unroll
    for (int fm = 0; fm < 4; ++fm) {
        int pr = fm * 16 + l15;
        int ki = k0 + (pr >> 3);
        int li = l0 + (pr & 7);
        float vm = (ki < kHW && li < kHW) ? 1.f : 0.f;
#pragma unroll
        for (int fn = 0; fn < 4; ++fn) {
            f32x4 b3v = *(const f32x4*)(b3 + wn * 64 + fn * 16 + kg * 4);
#pragma unroll
            for (int r = 0; r < 4; ++r)
                s[fn][r] += vm * fmaxf(acc[fn][fm][r] + b3v[r], 0.f);
        }
    }
#pragma unroll
    for (int fn = 0; fn < 4; ++fn)
#pragma unroll
        for (int r = 0; r < 4; ++r) {
            s[fn][r] += __shfl_xor(s[fn][r], 1);
            s[fn][r] += __shfl_xor(s[fn][r], 2);
            s[fn][r] += __shfl_xor(s[fn][r], 4);
            s[fn][r] += __shfl_xor(s[fn][r], 8);
        }
    if (l15 == 0) {
        float* op = out + (b << 8) + wn * 64 + kg * 4;
#pragma unroll
        for (int fn = 0; fn < 4; ++fn)
#pragma unroll
            for (int r = 0; r < 4; ++r)
                atomicAdd(op + fn * 16 + r, s[fn][r]);
    }
}

extern "C" void kernel_launch(void* const* d_in, const int* in_sizes, int n_in,
                              void* d_out, int out_size, void* d_ws, size_t ws_size,
                              hipStream_t stream) {
    const float* im = (const float*)d_in[0];
    const float* pw = (const float*)d_in[3];
    const float* pb = (const float*)d_in[4];
    const float* w1 = (const float*)d_in[5];
    const float* b1 = (const float*)d_in[6];
    const float* w2 = (const float*)d_in[7];
    const float* b2 = (const float*)d_in[8];
    const float* w3 = (const float*)d_in[9];
    const float* b3 = (const float*)d_in[10];
    float* out = (float*)d_out;

    float* al  = (float*)d_ws;            // 8*196*256
    float* ak  = al + 8 * 196 * 256;
    u16* pwi  = (u16*)(ak + 8 * 196 * 256);  // [64 k8-blk][256 n][8 k]
    u16* w1li = pwi + 512 * 256;             // [32 k8-blk][256 n][8 k]
    u16* w1ki = w1li + 256 * 256;
    u16* w2i  = w1ki + 256 * 256;
    u16* w3i  = w2i + 256 * 256;

    hipLaunchKernelGGL(k_prep, dim3(1544), dim3(256), 0, stream,
                       pw, pwi, w1, w1li, w1ki, w2, w2i, w3, w3i, out);
    hipLaunchKernelGGL(k_xa3, dim3(14, 8), dim3(256), 0, stream,
                       im, pwi, pb, w1li, w1ki, al, ak);
    hipLaunchKernelGGL(k_main7, dim3(kLC, kKC, 8), dim3(256), 0, stream,
                       ak, al, b1, w2i, b2, w3i, b3, out);
}

// Round 12
// 133.188 us; speedup vs baseline: 2.5773x; 1.6134x over previous
//
#include <hip/hip_runtime.h>
#include <hip/hip_bf16.h>

typedef unsigned short u16;
typedef float  f32x4  __attribute__((ext_vector_type(4)));
typedef __bf16 bf16x8 __attribute__((ext_vector_type(8)));
typedef unsigned short u16x8 __attribute__((ext_vector_type(8)));
typedef unsigned short u16x4 __attribute__((ext_vector_type(4)));

__device__ __forceinline__ u16 f2bfu(float f) {
    __hip_bfloat16 h = __float2bfloat16(f);
    return __builtin_bit_cast(unsigned short, h);
}

constexpr int kHW = 196;   // 14*14
constexpr int kKC = 13;    // ceil(196/16) k-chunks (16 k rows per tile)
constexpr int kLC = 25;    // ceil(196/8)  l-chunks (8 l rows per tile)
constexpr int kChunks = kKC * kLC;  // 325 per batch

// ---------------- prep: interleave weights [k>>3][n][k8] bf16 ----------------
__global__ __launch_bounds__(256)
void k_prep(const float* __restrict__ pw, u16* __restrict__ pwi,
            const float* __restrict__ w1, u16* __restrict__ w1li, u16* __restrict__ w1ki,
            const float* __restrict__ w2, u16* __restrict__ w2i,
            const float* __restrict__ w3, u16* __restrict__ w3i) {
    int id = blockIdx.x;
    int n = threadIdx.x;
    if (id < 512) {
        int k = id;
        pwi[((k >> 3) << 11) + (n << 3) + (k & 7)] = f2bfu(pw[n * 512 + k]);
    } else {
        int k = (id - 512) & 255;
        int idx = ((k >> 3) << 11) + (n << 3) + (k & 7);
        if (id < 768)       w1li[idx] = f2bfu(w1[k * 256 + n]);
        else if (id < 1024) w1ki[idx] = f2bfu(w1[(k + 256) * 256 + n]);
        else if (id < 1280) w2i[idx]  = f2bfu(w2[k * 256 + n]);
        else                w3i[idx]  = f2bfu(w3[k * 256 + n]);
    }
}

// ---------------- MFMA prologue: xf then al/ak. grid (14, 8), 256 thr ----------------
__global__ __launch_bounds__(256, 2)
void k_xa3(const float* __restrict__ im, const u16* __restrict__ pwi,
           const float* __restrict__ pb, const u16* __restrict__ w1li,
           const u16* __restrict__ w1ki, float* __restrict__ al,
           float* __restrict__ ak) {
    __shared__ u16 imT[16 * 512];   // [p][i] bf16, swizzled rows (1KB), 16KB
    __shared__ u16 xfs[16 * 256];   // [p][c] bf16, swizzled rows (512B), 8KB
    const int tid = threadIdx.x;
    const int b = blockIdx.y;
    const int p0 = blockIdx.x * 14;

    {
        int t4 = tid & 3;
        int ibase = tid >> 2;
#pragma unroll
        for (int it = 0; it < 8; ++it) {
            int i = it * 64 + ibase;
            const float* src = im + (b * 512 + i) * kHW;
#pragma unroll
            for (int j = 0; j < 4; ++j) {
                int prow = t4 * 4 + j;
                int p = p0 + prow; if (p > 195) p = 195;
                int byte = (prow << 10) + (i << 1);
                byte ^= (prow & 7) << 4;
                *(u16*)((char*)imT + byte) = f2bfu(src[p]);
            }
        }
    }
    __syncthreads();

    const int lane = tid & 63;
    const int wn = tid >> 6;
    const int l15 = lane & 15;
    const int kg = lane >> 4;
    const int wbase = (wn * 64 + l15) << 3;

    f32x4 acc[4];
#pragma unroll
    for (int fn = 0; fn < 4; ++fn) acc[fn] = f32x4{0.f, 0.f, 0.f, 0.f};
    for (int kk = 0; kk < 16; ++kk) {
        int kb = kk * 32 + kg * 8;
        int byte = (l15 << 10) + (kb << 1);
        byte ^= (l15 & 7) << 4;
        bf16x8 hb = __builtin_bit_cast(bf16x8, *(const u16x8*)((const char*)imT + byte));
        const u16* wp = pwi + ((((kk << 2) + kg) << 11) + wbase);
#pragma unroll
        for (int fn = 0; fn < 4; ++fn) {
            bf16x8 aw = __builtin_bit_cast(bf16x8, *(const u16x8*)(wp + (fn << 7)));
            acc[fn] = __builtin_amdgcn_mfma_f32_16x16x32_bf16(aw, hb, acc[fn], 0, 0, 0);
        }
    }
#pragma unroll
    for (int fn = 0; fn < 4; ++fn) {
        f32x4 pbv = *(const f32x4*)(pb + wn * 64 + fn * 16 + kg * 4);
        u16x4 pv;
#pragma unroll
        for (int r = 0; r < 4; ++r) pv[r] = f2bfu(acc[fn][r] + pbv[r]);
        int byte = (l15 << 9) + ((wn * 64 + fn * 16 + kg * 4) << 1);
        byte ^= (l15 & 7) << 4;
        *(u16x4*)((char*)xfs + byte) = pv;
    }
    __syncthreads();

    const int p = p0 + l15;
    const bool valid = (l15 < 14) && (p < kHW);
#pragma unroll
    for (int sel = 0; sel < 2; ++sel) {
        const u16* wsrc = sel ? w1ki : w1li;
        f32x4 a2[4];
#pragma unroll
        for (int fn = 0; fn < 4; ++fn) a2[fn] = f32x4{0.f, 0.f, 0.f, 0.f};
        for (int kk = 0; kk < 8; ++kk) {
            int kb = kk * 32 + kg * 8;
            int byte = (l15 << 9) + (kb << 1);
            byte ^= (l15 & 7) << 4;
            bf16x8 hb = __builtin_bit_cast(bf16x8, *(const u16x8*)((const char*)xfs + byte));
            const u16* wp = wsrc + ((((kk << 2) + kg) << 11) + wbase);
#pragma unroll
            for (int fn = 0; fn < 4; ++fn) {
                bf16x8 aw = __builtin_bit_cast(bf16x8, *(const u16x8*)(wp + (fn << 7)));
                a2[fn] = __builtin_amdgcn_mfma_f32_16x16x32_bf16(aw, hb, a2[fn], 0, 0, 0);
            }
        }
        if (valid) {
            float* dst = (sel ? ak : al) + ((b * kHW + p) << 8) + wn * 64 + kg * 4;
#pragma unroll
            for (int fn = 0; fn < 4; ++fn) *(f32x4*)(dst + fn * 16) = a2[fn];
        }
    }
}

// ---------------- main v9: 128-pair tiles to halve weight L2 traffic per FLOP ------
// grid (25 lc, 13 kc, 8 b) = 2600 blocks, block 256 (4 waves; wave = ch quarter).
// Tile: (16 k x 8 l) = 128 pairs x 256 ch. acc[4][8] = 128 AGPR -> (256,2), no spill
// (cap 256, est ~210 live). LDS 64KB (h1/h2 only) -> 2 blocks/CU.
__global__ __launch_bounds__(256, 2)
void k_main9(const float* __restrict__ ak, const float* __restrict__ al,
             const float* __restrict__ b1, const u16* __restrict__ w2i,
             const float* __restrict__ b2, const u16* __restrict__ w3i,
             const float* __restrict__ b3, float* __restrict__ part) {
    __shared__ u16 smem[128 * 256];  // 64 KB: h1, then h2 in-place
    const int tid = threadIdx.x;
    const int lc = blockIdx.x, kc = blockIdx.y, b = blockIdx.z;
    const int k0 = kc * 16, l0 = lc * 8;

    // ---- build h1 = relu(ak[k]+al[l]+b1) -> bf16 LDS [pair][ch] (from L2 direct) ----
    {
        const int cc = tid & 31;
        f32x4 c0v = *(const f32x4*)(b1 + (cc << 3));
        f32x4 c1v = *(const f32x4*)(b1 + (cc << 3) + 4);
#pragma unroll
        for (int it = 0; it < 16; ++it) {
            int row = (it * 256 + tid) >> 5;  // 0..127 = (ki-k0)*8 + (li-l0)
            int ki = k0 + (row >> 3); if (ki > 195) ki = 195;
            int li = l0 + (row & 7);  if (li > 195) li = 195;
            const float* akp = ak + ((b * kHW + ki) << 8) + (cc << 3);
            const float* alp = al + ((b * kHW + li) << 8) + (cc << 3);
            f32x4 k0v = *(const f32x4*)akp;
            f32x4 k1v = *(const f32x4*)(akp + 4);
            f32x4 l0v = *(const f32x4*)alp;
            f32x4 l1v = *(const f32x4*)(alp + 4);
            u16x8 v;
#pragma unroll
            for (int j = 0; j < 4; ++j) {
                v[j]     = f2bfu(fmaxf(k0v[j] + l0v[j] + c0v[j], 0.f));
                v[4 + j] = f2bfu(fmaxf(k1v[j] + l1v[j] + c1v[j], 0.f));
            }
            int byte = (row << 9) + (cc << 4);
            byte ^= (row & 7) << 4;
            *(u16x8*)((char*)smem + byte) = v;
        }
    }
    __syncthreads();

    const int lane = tid & 63;
    const int wn = tid >> 6;   // wave = ch quarter 0..3
    const int l15 = lane & 15;
    const int kg = lane >> 4;  // 0..3
    const int wbase = (wn * 64 + l15) << 3;

    f32x4 acc[4][8];  // [fn ch-frag][fm pair-frag], reused for both GEMMs

    // ---- GEMM1: h2^T = w2 x h1^T ----
#pragma unroll
    for (int fn = 0; fn < 4; ++fn)
#pragma unroll
        for (int fm = 0; fm < 8; ++fm) acc[fn][fm] = f32x4{0.f, 0.f, 0.f, 0.f};
    for (int kk = 0; kk < 8; ++kk) {
        int kb = kk * 32 + kg * 8;
        bf16x8 hb[8];
#pragma unroll
        for (int fm = 0; fm < 8; ++fm) {
            int row = fm * 16 + l15;
            int byte = (row << 9) + (kb << 1);
            byte ^= (row & 7) << 4;
            hb[fm] = __builtin_bit_cast(bf16x8, *(const u16x8*)((const char*)smem + byte));
        }
        const u16* wp = w2i + ((((kk << 2) + kg) << 11) + wbase);
#pragma unroll
        for (int fn = 0; fn < 4; ++fn) {
            bf16x8 aw = __builtin_bit_cast(bf16x8, *(const u16x8*)(wp + (fn << 7)));
#pragma unroll
            for (int fm = 0; fm < 8; ++fm)
                acc[fn][fm] = __builtin_amdgcn_mfma_f32_16x16x32_bf16(aw, hb[fm], acc[fn][fm], 0, 0, 0);
        }
    }
    __syncthreads();

    // ---- epilogue: h2 = relu(D1 + b2) -> bf16 LDS, packed 8B writes ----
#pragma unroll
    for (int fn = 0; fn < 4; ++fn) {
        f32x4 b2v = *(const f32x4*)(b2 + wn * 64 + fn * 16 + kg * 4);
#pragma unroll
        for (int fm = 0; fm < 8; ++fm) {
            int prow = fm * 16 + l15;
            u16x4 pv;
#pragma unroll
            for (int r = 0; r < 4; ++r)
                pv[r] = f2bfu(fmaxf(acc[fn][fm][r] + b2v[r], 0.f));
            int byte = (prow << 9) + ((wn * 64 + fn * 16 + kg * 4) << 1);
            byte ^= (prow & 7) << 4;
            *(u16x4*)((char*)smem + byte) = pv;
        }
    }
    __syncthreads();

    // ---- GEMM2: h3^T = w3 x h2^T ----
#pragma unroll
    for (int fn = 0; fn < 4; ++fn)
#pragma unroll
        for (int fm = 0; fm < 8; ++fm) acc[fn][fm] = f32x4{0.f, 0.f, 0.f, 0.f};
    for (int kk = 0; kk < 8; ++kk) {
        int kb = kk * 32 + kg * 8;
        bf16x8 hb[8];
#pragma unroll
        for (int fm = 0; fm < 8; ++fm) {
            int row = fm * 16 + l15;
            int byte = (row << 9) + (kb << 1);
            byte ^= (row & 7) << 4;
            hb[fm] = __builtin_bit_cast(bf16x8, *(const u16x8*)((const char*)smem + byte));
        }
        const u16* wp = w3i + ((((kk << 2) + kg) << 11) + wbase);
#pragma unroll
        for (int fn = 0; fn < 4; ++fn) {
            bf16x8 aw = __builtin_bit_cast(bf16x8, *(const u16x8*)(wp + (fn << 7)));
#pragma unroll
            for (int fm = 0; fm < 8; ++fm)
                acc[fn][fm] = __builtin_amdgcn_mfma_f32_16x16x32_bf16(aw, hb[fm], acc[fn][fm], 0, 0, 0);
        }
    }

    // ---- masked col-sum + 16-lane reduce + store to part ----
    float s[4][4] = {};
#pragma unroll
    for (int fm = 0; fm < 8; ++fm) {
        int pr = fm * 16 + l15;
        int ki = k0 + (pr >> 3);
        int li = l0 + (pr & 7);
        float vm = (ki < kHW && li < kHW) ? 1.f : 0.f;
#pragma unroll
        for (int fn = 0; fn < 4; ++fn) {
            f32x4 b3v = *(const f32x4*)(b3 + wn * 64 + fn * 16 + kg * 4);
#pragma unroll
            for (int r = 0; r < 4; ++r)
                s[fn][r] += vm * fmaxf(acc[fn][fm][r] + b3v[r], 0.f);
        }
    }
#pragma unroll
    for (int fn = 0; fn < 4; ++fn)
#pragma unroll
        for (int r = 0; r < 4; ++r) {
            s[fn][r] += __shfl_xor(s[fn][r], 1);
            s[fn][r] += __shfl_xor(s[fn][r], 2);
            s[fn][r] += __shfl_xor(s[fn][r], 4);
            s[fn][r] += __shfl_xor(s[fn][r], 8);
        }
    if (l15 == 0) {
        int chunkid = (b * kKC + kc) * kLC + lc;
        float* pp = part + chunkid * 256 + wn * 64 + kg * 4;
#pragma unroll
        for (int fn = 0; fn < 4; ++fn)
            *(f32x4*)(pp + fn * 16) = f32x4{s[fn][0], s[fn][1], s[fn][2], s[fn][3]};
    }
}

// ---------------- final reduce over 325 chunks per batch ----------------
__global__ __launch_bounds__(1024)
void k_reduce(const float* __restrict__ part, float* __restrict__ out) {
    __shared__ float red[4][256];
    int b = blockIdx.x;
    int c = threadIdx.x & 255;
    int stripe = threadIdx.x >> 8;
    const float* p = part + (b * kChunks) * 256 + c;
    float s = 0.f;
    for (int j = stripe; j < kChunks; j += 4) s += p[j * 256];
    red[stripe][c] = s;
    __syncthreads();
    if (threadIdx.x < 256)
        out[b * 256 + threadIdx.x] = red[0][threadIdx.x] + red[1][threadIdx.x] +
                                     red[2][threadIdx.x] + red[3][threadIdx.x];
}

extern "C" void kernel_launch(void* const* d_in, const int* in_sizes, int n_in,
                              void* d_out, int out_size, void* d_ws, size_t ws_size,
                              hipStream_t stream) {
    const float* im = (const float*)d_in[0];
    const float* pw = (const float*)d_in[3];
    const float* pb = (const float*)d_in[4];
    const float* w1 = (const float*)d_in[5];
    const float* b1 = (const float*)d_in[6];
    const float* w2 = (const float*)d_in[7];
    const float* b2 = (const float*)d_in[8];
    const float* w3 = (const float*)d_in[9];
    const float* b3 = (const float*)d_in[10];
    float* out = (float*)d_out;

    float* al  = (float*)d_ws;            // 8*196*256
    float* ak  = al + 8 * 196 * 256;
    u16* pwi  = (u16*)(ak + 8 * 196 * 256);  // [64 k8-blk][256 n][8 k]
    u16* w1li = pwi + 512 * 256;             // [32 k8-blk][256 n][8 k]
    u16* w1ki = w1li + 256 * 256;
    u16* w2i  = w1ki + 256 * 256;
    u16* w3i  = w2i + 256 * 256;
    float* part = (float*)(w3i + 256 * 256); // [8*325][256] = 2.66 MB

    hipLaunchKernelGGL(k_prep, dim3(1536), dim3(256), 0, stream,
                       pw, pwi, w1, w1li, w1ki, w2, w2i, w3, w3i);
    hipLaunchKernelGGL(k_xa3, dim3(14, 8), dim3(256), 0, stream,
                       im, pwi, pb, w1li, w1ki, al, ak);
    hipLaunchKernelGGL(k_main9, dim3(kLC, kKC, 8), dim3(256), 0, stream,
                       ak, al, b1, w2i, b2, w3i, b3, part);
    hipLaunchKernelGGL(k_reduce, dim3(8), dim3(1024), 0, stream, part, out);
}

// Round 13
// 131.568 us; speedup vs baseline: 2.6090x; 1.0123x over previous
//
#include <hip/hip_runtime.h>
#include <hip/hip_bf16.h>

typedef unsigned short u16;
typedef float  f32x4  __attribute__((ext_vector_type(4)));
typedef __bf16 bf16x8 __attribute__((ext_vector_type(8)));
typedef unsigned short u16x8 __attribute__((ext_vector_type(8)));
typedef unsigned short u16x4 __attribute__((ext_vector_type(4)));

__device__ __forceinline__ u16 f2bfu(float f) {
    __hip_bfloat16 h = __float2bfloat16(f);
    return __builtin_bit_cast(unsigned short, h);
}

constexpr int kHW = 196;   // 14*14
constexpr int kKC = 13;    // ceil(196/16) k-chunks (16 k rows per tile)
constexpr int kLC = 25;    // ceil(196/8)  l-chunks (8 l rows per tile)
constexpr int kChunks = kKC * kLC;  // 325 per batch

// ---------------- prep: interleave weights [k>>3][n][k8] bf16 ----------------
__global__ __launch_bounds__(256)
void k_prep(const float* __restrict__ pw, u16* __restrict__ pwi,
            const float* __restrict__ w1, u16* __restrict__ w1li, u16* __restrict__ w1ki,
            const float* __restrict__ w2, u16* __restrict__ w2i,
            const float* __restrict__ w3, u16* __restrict__ w3i) {
    int id = blockIdx.x;
    int n = threadIdx.x;
    if (id < 512) {
        int k = id;
        pwi[((k >> 3) << 11) + (n << 3) + (k & 7)] = f2bfu(pw[n * 512 + k]);
    } else {
        int k = (id - 512) & 255;
        int idx = ((k >> 3) << 11) + (n << 3) + (k & 7);
        if (id < 768)       w1li[idx] = f2bfu(w1[k * 256 + n]);
        else if (id < 1024) w1ki[idx] = f2bfu(w1[(k + 256) * 256 + n]);
        else if (id < 1280) w2i[idx]  = f2bfu(w2[k * 256 + n]);
        else                w3i[idx]  = f2bfu(w3[k * 256 + n]);
    }
}

// ---------------- MFMA prologue: xf then al/ak. grid (14, 8), 256 thr ----------------
__global__ __launch_bounds__(256, 2)
void k_xa3(const float* __restrict__ im, const u16* __restrict__ pwi,
           const float* __restrict__ pb, const u16* __restrict__ w1li,
           const u16* __restrict__ w1ki, float* __restrict__ al,
           float* __restrict__ ak) {
    __shared__ u16 imT[16 * 512];   // [p][i] bf16, swizzled rows (1KB), 16KB
    __shared__ u16 xfs[16 * 256];   // [p][c] bf16, swizzled rows (512B), 8KB
    const int tid = threadIdx.x;
    const int b = blockIdx.y;
    const int p0 = blockIdx.x * 14;

    {
        int t4 = tid & 3;
        int ibase = tid >> 2;
#pragma unroll
        for (int it = 0; it < 8; ++it) {
            int i = it * 64 + ibase;
            const float* src = im + (b * 512 + i) * kHW;
#pragma unroll
            for (int j = 0; j < 4; ++j) {
                int prow = t4 * 4 + j;
                int p = p0 + prow; if (p > 195) p = 195;
                int byte = (prow << 10) + (i << 1);
                byte ^= (prow & 7) << 4;
                *(u16*)((char*)imT + byte) = f2bfu(src[p]);
            }
        }
    }
    __syncthreads();

    const int lane = tid & 63;
    const int wn = tid >> 6;
    const int l15 = lane & 15;
    const int kg = lane >> 4;
    const int wbase = (wn * 64 + l15) << 3;

    f32x4 acc[4];
#pragma unroll
    for (int fn = 0; fn < 4; ++fn) acc[fn] = f32x4{0.f, 0.f, 0.f, 0.f};
    for (int kk = 0; kk < 16; ++kk) {
        int kb = kk * 32 + kg * 8;
        int byte = (l15 << 10) + (kb << 1);
        byte ^= (l15 & 7) << 4;
        bf16x8 hb = __builtin_bit_cast(bf16x8, *(const u16x8*)((const char*)imT + byte));
        const u16* wp = pwi + ((((kk << 2) + kg) << 11) + wbase);
#pragma unroll
        for (int fn = 0; fn < 4; ++fn) {
            bf16x8 aw = __builtin_bit_cast(bf16x8, *(const u16x8*)(wp + (fn << 7)));
            acc[fn] = __builtin_amdgcn_mfma_f32_16x16x32_bf16(aw, hb, acc[fn], 0, 0, 0);
        }
    }
#pragma unroll
    for (int fn = 0; fn < 4; ++fn) {
        f32x4 pbv = *(const f32x4*)(pb + wn * 64 + fn * 16 + kg * 4);
        u16x4 pv;
#pragma unroll
        for (int r = 0; r < 4; ++r) pv[r] = f2bfu(acc[fn][r] + pbv[r]);
        int byte = (l15 << 9) + ((wn * 64 + fn * 16 + kg * 4) << 1);
        byte ^= (l15 & 7) << 4;
        *(u16x4*)((char*)xfs + byte) = pv;
    }
    __syncthreads();

    const int p = p0 + l15;
    const bool valid = (l15 < 14) && (p < kHW);
#pragma unroll
    for (int sel = 0; sel < 2; ++sel) {
        const u16* wsrc = sel ? w1ki : w1li;
        f32x4 a2[4];
#pragma unroll
        for (int fn = 0; fn < 4; ++fn) a2[fn] = f32x4{0.f, 0.f, 0.f, 0.f};
        for (int kk = 0; kk < 8; ++kk) {
            int kb = kk * 32 + kg * 8;
            int byte = (l15 << 9) + (kb << 1);
            byte ^= (l15 & 7) << 4;
            bf16x8 hb = __builtin_bit_cast(bf16x8, *(const u16x8*)((const char*)xfs + byte));
            const u16* wp = wsrc + ((((kk << 2) + kg) << 11) + wbase);
#pragma unroll
            for (int fn = 0; fn < 4; ++fn) {
                bf16x8 aw = __builtin_bit_cast(bf16x8, *(const u16x8*)(wp + (fn << 7)));
                a2[fn] = __builtin_amdgcn_mfma_f32_16x16x32_bf16(aw, hb, a2[fn], 0, 0, 0);
            }
        }
        if (valid) {
            float* dst = (sel ? ak : al) + ((b * kHW + p) << 8) + wn * 64 + kg * 4;
#pragma unroll
            for (int fn = 0; fn < 4; ++fn) *(f32x4*)(dst + fn * 16) = a2[fn];
        }
    }
}

// ---------------- main v10: 128-pair tiles, low-live-reg kk-loop (no spill) --------
// grid (25 lc, 13 kc, 8 b) = 2600 blocks, block 256 (4 waves; wave = ch quarter).
// Tile: (16 k x 8 l) = 128 pairs x 256 ch. acc[4][8]=128 AGPR; aw[4] preloaded,
// hb streamed one-at-a-time -> peak live ~190 < 256 cap at (256,2).
__global__ __launch_bounds__(256, 2)
void k_main10(const float* __restrict__ ak, const float* __restrict__ al,
              const float* __restrict__ b1, const u16* __restrict__ w2i,
              const float* __restrict__ b2, const u16* __restrict__ w3i,
              const float* __restrict__ b3, float* __restrict__ part) {
    __shared__ u16 smem[128 * 256];  // 64 KB: h1, then h2 in-place
    const int tid = threadIdx.x;
    const int lc = blockIdx.x, kc = blockIdx.y, b = blockIdx.z;
    const int k0 = kc * 16, l0 = lc * 8;

    // ---- build h1 = relu(ak[k]+al[l]+b1) -> bf16 LDS [pair][ch] ----
    {
        const int cc = tid & 31;
        f32x4 c0v = *(const f32x4*)(b1 + (cc << 3));
        f32x4 c1v = *(const f32x4*)(b1 + (cc << 3) + 4);
#pragma unroll
        for (int it = 0; it < 16; ++it) {
            int row = (it * 256 + tid) >> 5;  // 0..127 = (ki-k0)*8 + (li-l0)
            int ki = k0 + (row >> 3); if (ki > 195) ki = 195;
            int li = l0 + (row & 7);  if (li > 195) li = 195;
            const float* akp = ak + ((b * kHW + ki) << 8) + (cc << 3);
            const float* alp = al + ((b * kHW + li) << 8) + (cc << 3);
            f32x4 k0v = *(const f32x4*)akp;
            f32x4 k1v = *(const f32x4*)(akp + 4);
            f32x4 l0v = *(const f32x4*)alp;
            f32x4 l1v = *(const f32x4*)(alp + 4);
            u16x8 v;
#pragma unroll
            for (int j = 0; j < 4; ++j) {
                v[j]     = f2bfu(fmaxf(k0v[j] + l0v[j] + c0v[j], 0.f));
                v[4 + j] = f2bfu(fmaxf(k1v[j] + l1v[j] + c1v[j], 0.f));
            }
            int byte = (row << 9) + (cc << 4);
            byte ^= (row & 7) << 4;
            *(u16x8*)((char*)smem + byte) = v;
        }
    }
    __syncthreads();

    const int lane = tid & 63;
    const int wn = tid >> 6;   // wave = ch quarter 0..3
    const int l15 = lane & 15;
    const int kg = lane >> 4;  // 0..3
    const int wbase = (wn * 64 + l15) << 3;

    f32x4 acc[4][8];  // [fn ch-frag][fm pair-frag], reused for both GEMMs

    // ---- GEMM1: h2^T = w2 x h1^T (aw preloaded, hb streamed) ----
#pragma unroll
    for (int fn = 0; fn < 4; ++fn)
#pragma unroll
        for (int fm = 0; fm < 8; ++fm) acc[fn][fm] = f32x4{0.f, 0.f, 0.f, 0.f};
    for (int kk = 0; kk < 8; ++kk) {
        int kb = kk * 32 + kg * 8;
        const u16* wp = w2i + ((((kk << 2) + kg) << 11) + wbase);
        bf16x8 aw[4];
#pragma unroll
        for (int fn = 0; fn < 4; ++fn)
            aw[fn] = __builtin_bit_cast(bf16x8, *(const u16x8*)(wp + (fn << 7)));
#pragma unroll
        for (int fm = 0; fm < 8; ++fm) {
            int row = fm * 16 + l15;
            int byte = (row << 9) + (kb << 1);
            byte ^= (row & 7) << 4;
            bf16x8 hb = __builtin_bit_cast(bf16x8, *(const u16x8*)((const char*)smem + byte));
#pragma unroll
            for (int fn = 0; fn < 4; ++fn)
                acc[fn][fm] = __builtin_amdgcn_mfma_f32_16x16x32_bf16(aw[fn], hb, acc[fn][fm], 0, 0, 0);
        }
    }
    __syncthreads();

    // ---- epilogue: h2 = relu(D1 + b2) -> bf16 LDS, packed 8B writes ----
#pragma unroll
    for (int fn = 0; fn < 4; ++fn) {
        f32x4 b2v = *(const f32x4*)(b2 + wn * 64 + fn * 16 + kg * 4);
#pragma unroll
        for (int fm = 0; fm < 8; ++fm) {
            int prow = fm * 16 + l15;
            u16x4 pv;
#pragma unroll
            for (int r = 0; r < 4; ++r)
                pv[r] = f2bfu(fmaxf(acc[fn][fm][r] + b2v[r], 0.f));
            int byte = (prow << 9) + ((wn * 64 + fn * 16 + kg * 4) << 1);
            byte ^= (prow & 7) << 4;
            *(u16x4*)((char*)smem + byte) = pv;
        }
    }
    __syncthreads();

    // ---- GEMM2: h3^T = w3 x h2^T ----
#pragma unroll
    for (int fn = 0; fn < 4; ++fn)
#pragma unroll
        for (int fm = 0; fm < 8; ++fm) acc[fn][fm] = f32x4{0.f, 0.f, 0.f, 0.f};
    for (int kk = 0; kk < 8; ++kk) {
        int kb = kk * 32 + kg * 8;
        const u16* wp = w3i + ((((kk << 2) + kg) << 11) + wbase);
        bf16x8 aw[4];
#pragma unroll
        for (int fn = 0; fn < 4; ++fn)
            aw[fn] = __builtin_bit_cast(bf16x8, *(const u16x8*)(wp + (fn << 7)));
#pragma unroll
        for (int fm = 0; fm < 8; ++fm) {
            int row = fm * 16 + l15;
            int byte = (row << 9) + (kb << 1);
            byte ^= (row & 7) << 4;
            bf16x8 hb = __builtin_bit_cast(bf16x8, *(const u16x8*)((const char*)smem + byte));
#pragma unroll
            for (int fn = 0; fn < 4; ++fn)
                acc[fn][fm] = __builtin_amdgcn_mfma_f32_16x16x32_bf16(aw[fn], hb, acc[fn][fm], 0, 0, 0);
        }
    }

    // ---- masked col-sum + 16-lane reduce + store to part ----
    float s[4][4] = {};
#pragma unroll
    for (int fm = 0; fm < 8; ++fm) {
        int pr = fm * 16 + l15;
        int ki = k0 + (pr >> 3);
        int li = l0 + (pr & 7);
        float vm = (ki < kHW && li < kHW) ? 1.f : 0.f;
#pragma unroll
        for (int fn = 0; fn < 4; ++fn) {
            f32x4 b3v = *(const f32x4*)(b3 + wn * 64 + fn * 16 + kg * 4);
#pragma unroll
            for (int r = 0; r < 4; ++r)
                s[fn][r] += vm * fmaxf(acc[fn][fm][r] + b3v[r], 0.f);
        }
    }
#pragma unroll
    for (int fn = 0; fn < 4; ++fn)
#pragma unroll
        for (int r = 0; r < 4; ++r) {
            s[fn][r] += __shfl_xor(s[fn][r], 1);
            s[fn][r] += __shfl_xor(s[fn][r], 2);
            s[fn][r] += __shfl_xor(s[fn][r], 4);
            s[fn][r] += __shfl_xor(s[fn][r], 8);
        }
    if (l15 == 0) {
        int chunkid = (b * kKC + kc) * kLC + lc;
        float* pp = part + chunkid * 256 + wn * 64 + kg * 4;
#pragma unroll
        for (int fn = 0; fn < 4; ++fn)
            *(f32x4*)(pp + fn * 16) = f32x4{s[fn][0], s[fn][1], s[fn][2], s[fn][3]};
    }
}

// ---------------- final reduce over 325 chunks per batch ----------------
__global__ __launch_bounds__(1024)
void k_reduce(const float* __restrict__ part, float* __restrict__ out) {
    __shared__ float red[4][256];
    int b = blockIdx.x;
    int c = threadIdx.x & 255;
    int stripe = threadIdx.x >> 8;
    const float* p = part + (b * kChunks) * 256 + c;
    float s = 0.f;
    for (int j = stripe; j < kChunks; j += 4) s += p[j * 256];
    red[stripe][c] = s;
    __syncthreads();
    if (threadIdx.x < 256)
        out[b * 256 + threadIdx.x] = red[0][threadIdx.x] + red[1][threadIdx.x] +
                                     red[2][threadIdx.x] + red[3][threadIdx.x];
}

extern "C" void kernel_launch(void* const* d_in, const int* in_sizes, int n_in,
                              void* d_out, int out_size, void* d_ws, size_t ws_size,
                              hipStream_t stream) {
    const float* im = (const float*)d_in[0];
    const float* pw = (const float*)d_in[3];
    const float* pb = (const float*)d_in[4];
    const float* w1 = (const float*)d_in[5];
    const float* b1 = (const float*)d_in[6];
    const float* w2 = (const float*)d_in[7];
    const float* b2 = (const float*)d_in[8];
    const float* w3 = (const float*)d_in[9];
    const float* b3 = (const float*)d_in[10];
    float* out = (float*)d_out;

    float* al  = (float*)d_ws;            // 8*196*256
    float* ak  = al + 8 * 196 * 256;
    u16* pwi  = (u16*)(ak + 8 * 196 * 256);  // [64 k8-blk][256 n][8 k]
    u16* w1li = pwi + 512 * 256;             // [32 k8-blk][256 n][8 k]
    u16* w1ki = w1li + 256 * 256;
    u16* w2i  = w1ki + 256 * 256;
    u16* w3i  = w2i + 256 * 256;
    float* part = (float*)(w3i + 256 * 256); // [8*325][256] = 2.66 MB

    hipLaunchKernelGGL(k_prep, dim3(1536), dim3(256), 0, stream,
                       pw, pwi, w1, w1li, w1ki, w2, w2i, w3, w3i);
    hipLaunchKernelGGL(k_xa3, dim3(14, 8), dim3(256), 0, stream,
                       im, pwi, pb, w1li, w1ki, al, ak);
    hipLaunchKernelGGL(k_main10, dim3(kLC, kKC, 8), dim3(256), 0, stream,
                       ak, al, b1, w2i, b2, w3i, b3, part);
    hipLaunchKernelGGL(k_reduce, dim3(8), dim3(1024), 0, stream, part, out);
}

// Round 14
// 129.117 us; speedup vs baseline: 2.6585x; 1.0190x over previous
//
#include <hip/hip_runtime.h>
#include <hip/hip_bf16.h>

typedef unsigned short u16;
typedef float  f32x4  __attribute__((ext_vector_type(4)));
typedef __bf16 bf16x8 __attribute__((ext_vector_type(8)));
typedef unsigned short u16x8 __attribute__((ext_vector_type(8)));
typedef unsigned short u16x4 __attribute__((ext_vector_type(4)));

__device__ __forceinline__ u16 f2bfu(float f) {
    __hip_bfloat16 h = __float2bfloat16(f);
    return __builtin_bit_cast(unsigned short, h);
}

constexpr int kHW = 196;   // 14*14
constexpr int kKC = 13;    // ceil(196/16) k-chunks (16 k rows per tile)
constexpr int kLC = 25;    // ceil(196/8)  l-chunks (8 l rows per tile)
constexpr int kChunks = kKC * kLC;  // 325 per batch

// ---------------- prep: interleave weights [k>>3][n][k8] bf16 ----------------
__global__ __launch_bounds__(256)
void k_prep(const float* __restrict__ pw, u16* __restrict__ pwi,
            const float* __restrict__ w1, u16* __restrict__ w1li, u16* __restrict__ w1ki,
            const float* __restrict__ w2, u16* __restrict__ w2i,
            const float* __restrict__ w3, u16* __restrict__ w3i) {
    int id = blockIdx.x;
    int n = threadIdx.x;
    if (id < 512) {
        int k = id;
        pwi[((k >> 3) << 11) + (n << 3) + (k & 7)] = f2bfu(pw[n * 512 + k]);
    } else {
        int k = (id - 512) & 255;
        int idx = ((k >> 3) << 11) + (n << 3) + (k & 7);
        if (id < 768)       w1li[idx] = f2bfu(w1[k * 256 + n]);
        else if (id < 1024) w1ki[idx] = f2bfu(w1[(k + 256) * 256 + n]);
        else if (id < 1280) w2i[idx]  = f2bfu(w2[k * 256 + n]);
        else                w3i[idx]  = f2bfu(w3[k * 256 + n]);
    }
}

// ---------------- MFMA prologue: xf then al/ak. grid (14, 8), 256 thr ----------------
__global__ __launch_bounds__(256, 2)
void k_xa3(const float* __restrict__ im, const u16* __restrict__ pwi,
           const float* __restrict__ pb, const u16* __restrict__ w1li,
           const u16* __restrict__ w1ki, float* __restrict__ al,
           float* __restrict__ ak) {
    __shared__ u16 imT[16 * 512];   // [p][i] bf16, swizzled rows (1KB), 16KB
    __shared__ u16 xfs[16 * 256];   // [p][c] bf16, swizzled rows (512B), 8KB
    const int tid = threadIdx.x;
    const int b = blockIdx.y;
    const int p0 = blockIdx.x * 14;

    {
        int t4 = tid & 3;
        int ibase = tid >> 2;
#pragma unroll
        for (int it = 0; it < 8; ++it) {
            int i = it * 64 + ibase;
            const float* src = im + (b * 512 + i) * kHW;
#pragma unroll
            for (int j = 0; j < 4; ++j) {
                int prow = t4 * 4 + j;
                int p = p0 + prow; if (p > 195) p = 195;
                int byte = (prow << 10) + (i << 1);
                byte ^= (prow & 7) << 4;
                *(u16*)((char*)imT + byte) = f2bfu(src[p]);
            }
        }
    }
    __syncthreads();

    const int lane = tid & 63;
    const int wn = tid >> 6;
    const int l15 = lane & 15;
    const int kg = lane >> 4;
    const int wbase = (wn * 64 + l15) << 3;

    f32x4 acc[4];
#pragma unroll
    for (int fn = 0; fn < 4; ++fn) acc[fn] = f32x4{0.f, 0.f, 0.f, 0.f};
    for (int kk = 0; kk < 16; ++kk) {
        int kb = kk * 32 + kg * 8;
        int byte = (l15 << 10) + (kb << 1);
        byte ^= (l15 & 7) << 4;
        bf16x8 hb = __builtin_bit_cast(bf16x8, *(const u16x8*)((const char*)imT + byte));
        const u16* wp = pwi + ((((kk << 2) + kg) << 11) + wbase);
#pragma unroll
        for (int fn = 0; fn < 4; ++fn) {
            bf16x8 aw = __builtin_bit_cast(bf16x8, *(const u16x8*)(wp + (fn << 7)));
            acc[fn] = __builtin_amdgcn_mfma_f32_16x16x32_bf16(aw, hb, acc[fn], 0, 0, 0);
        }
    }
#pragma unroll
    for (int fn = 0; fn < 4; ++fn) {
        f32x4 pbv = *(const f32x4*)(pb + wn * 64 + fn * 16 + kg * 4);
        u16x4 pv;
#pragma unroll
        for (int r = 0; r < 4; ++r) pv[r] = f2bfu(acc[fn][r] + pbv[r]);
        int byte = (l15 << 9) + ((wn * 64 + fn * 16 + kg * 4) << 1);
        byte ^= (l15 & 7) << 4;
        *(u16x4*)((char*)xfs + byte) = pv;
    }
    __syncthreads();

    const int p = p0 + l15;
    const bool valid = (l15 < 14) && (p < kHW);
#pragma unroll
    for (int sel = 0; sel < 2; ++sel) {
        const u16* wsrc = sel ? w1ki : w1li;
        f32x4 a2[4];
#pragma unroll
        for (int fn = 0; fn < 4; ++fn) a2[fn] = f32x4{0.f, 0.f, 0.f, 0.f};
        for (int kk = 0; kk < 8; ++kk) {
            int kb = kk * 32 + kg * 8;
            int byte = (l15 << 9) + (kb << 1);
            byte ^= (l15 & 7) << 4;
            bf16x8 hb = __builtin_bit_cast(bf16x8, *(const u16x8*)((const char*)xfs + byte));
            const u16* wp = wsrc + ((((kk << 2) + kg) << 11) + wbase);
#pragma unroll
            for (int fn = 0; fn < 4; ++fn) {
                bf16x8 aw = __builtin_bit_cast(bf16x8, *(const u16x8*)(wp + (fn << 7)));
                a2[fn] = __builtin_amdgcn_mfma_f32_16x16x32_bf16(aw, hb, a2[fn], 0, 0, 0);
            }
        }
        if (valid) {
            float* dst = (sel ? ak : al) + ((b * kHW + p) << 8) + wn * 64 + kg * 4;
#pragma unroll
            for (int fn = 0; fn < 4; ++fn) *(f32x4*)(dst + fn * 16) = a2[fn];
        }
    }
}

// ---------------- main v11: v10 + aw double-buffer prefetch across kk --------------
// grid (25 lc, 13 kc, 8 b) = 2600 blocks, block 256 (4 waves; wave = ch quarter).
// Tile: (16 k x 8 l) = 128 pairs x 256 ch. acc[4][8]=128 AGPR; awA/awB (+16 VGPR)
// prefetched one kk ahead; staging unroll cut to 4 to free arch VGPRs.
__global__ __launch_bounds__(256, 2)
void k_main11(const float* __restrict__ ak, const float* __restrict__ al,
              const float* __restrict__ b1, const u16* __restrict__ w2i,
              const float* __restrict__ b2, const u16* __restrict__ w3i,
              const float* __restrict__ b3, float* __restrict__ part) {
    __shared__ u16 smem[128 * 256];  // 64 KB: h1, then h2 in-place
    const int tid = threadIdx.x;
    const int lc = blockIdx.x, kc = blockIdx.y, b = blockIdx.z;
    const int k0 = kc * 16, l0 = lc * 8;

    // ---- build h1 = relu(ak[k]+al[l]+b1) -> bf16 LDS [pair][ch] ----
    {
        const int cc = tid & 31;
        f32x4 c0v = *(const f32x4*)(b1 + (cc << 3));
        f32x4 c1v = *(const f32x4*)(b1 + (cc << 3) + 4);
#pragma unroll 4
        for (int it = 0; it < 16; ++it) {
            int row = (it * 256 + tid) >> 5;  // 0..127 = (ki-k0)*8 + (li-l0)
            int ki = k0 + (row >> 3); if (ki > 195) ki = 195;
            int li = l0 + (row & 7);  if (li > 195) li = 195;
            const float* akp = ak + ((b * kHW + ki) << 8) + (cc << 3);
            const float* alp = al + ((b * kHW + li) << 8) + (cc << 3);
            f32x4 k0v = *(const f32x4*)akp;
            f32x4 k1v = *(const f32x4*)(akp + 4);
            f32x4 l0v = *(const f32x4*)alp;
            f32x4 l1v = *(const f32x4*)(alp + 4);
            u16x8 v;
#pragma unroll
            for (int j = 0; j < 4; ++j) {
                v[j]     = f2bfu(fmaxf(k0v[j] + l0v[j] + c0v[j], 0.f));
                v[4 + j] = f2bfu(fmaxf(k1v[j] + l1v[j] + c1v[j], 0.f));
            }
            int byte = (row << 9) + (cc << 4);
            byte ^= (row & 7) << 4;
            *(u16x8*)((char*)smem + byte) = v;
        }
    }
    __syncthreads();

    const int lane = tid & 63;
    const int wn = tid >> 6;   // wave = ch quarter 0..3
    const int l15 = lane & 15;
    const int kg = lane >> 4;  // 0..3
    const int wbase = (wn * 64 + l15) << 3;

    f32x4 acc[4][8];  // [fn ch-frag][fm pair-frag], reused for both GEMMs
    bf16x8 awA[4], awB[4];

// GEMM body: kk unrolled by 2 with A/B weight double-buffer. Static names only.
#define GEMM_DBUF(WSRC)                                                         \
    {                                                                           \
        const u16* wb_ = WSRC + wbase;                                          \
        _Pragma("unroll")                                                       \
        for (int fn = 0; fn < 4; ++fn)                                          \
            awA[fn] = __builtin_bit_cast(                                       \
                bf16x8, *(const u16x8*)(wb_ + (kg << 11) + (fn << 7)));         \
        _Pragma("unroll")                                                       \
        for (int kk = 0; kk < 8; kk += 2) {                                     \
            {                                                                   \
                const u16* wp1_ = wb_ + ((((kk + 1) << 2) + kg) << 11);         \
                _Pragma("unroll")                                               \
                for (int fn = 0; fn < 4; ++fn)                                  \
                    awB[fn] = __builtin_bit_cast(                               \
                        bf16x8, *(const u16x8*)(wp1_ + (fn << 7)));             \
            }                                                                   \
            {                                                                   \
                int kb_ = kk * 32 + kg * 8;                                     \
                _Pragma("unroll")                                               \
                for (int fm = 0; fm < 8; ++fm) {                                \
                    int row_ = fm * 16 + l15;                                   \
                    int byte_ = (row_ << 9) + (kb_ << 1);                       \
                    byte_ ^= (row_ & 7) << 4;                                   \
                    bf16x8 hb_ = __builtin_bit_cast(                            \
                        bf16x8, *(const u16x8*)((const char*)smem + byte_));    \
                    _Pragma("unroll")                                           \
                    for (int fn = 0; fn < 4; ++fn)                              \
                        acc[fn][fm] = __builtin_amdgcn_mfma_f32_16x16x32_bf16(  \
                            awA[fn], hb_, acc[fn][fm], 0, 0, 0);                \
                }                                                               \
            }                                                                   \
            if (kk + 2 < 8) {                                                   \
                const u16* wp2_ = wb_ + ((((kk + 2) << 2) + kg) << 11);         \
                _Pragma("unroll")                                               \
                for (int fn = 0; fn < 4; ++fn)                                  \
                    awA[fn] = __builtin_bit_cast(                               \
                        bf16x8, *(const u16x8*)(wp2_ + (fn << 7)));             \
            }                                                                   \
            {                                                                   \
                int kb_ = (kk + 1) * 32 + kg * 8;                               \
                _Pragma("unroll")                                               \
                for (int fm = 0; fm < 8; ++fm) {                                \
                    int row_ = fm * 16 + l15;                                   \
                    int byte_ = (row_ << 9) + (kb_ << 1);                       \
                    byte_ ^= (row_ & 7) << 4;                                   \
                    bf16x8 hb_ = __builtin_bit_cast(                            \
                        bf16x8, *(const u16x8*)((const char*)smem + byte_));    \
                    _Pragma("unroll")                                           \
                    for (int fn = 0; fn < 4; ++fn)                              \
                        acc[fn][fm] = __builtin_amdgcn_mfma_f32_16x16x32_bf16(  \
                            awB[fn], hb_, acc[fn][fm], 0, 0, 0);                \
                }                                                               \
            }                                                                   \
        }                                                                       \
    }

    // ---- GEMM1: h2^T = w2 x h1^T ----
#pragma unroll
    for (int fn = 0; fn < 4; ++fn)
#pragma unroll
        for (int fm = 0; fm < 8; ++fm) acc[fn][fm] = f32x4{0.f, 0.f, 0.f, 0.f};
    GEMM_DBUF(w2i)
    __syncthreads();

    // ---- epilogue: h2 = relu(D1 + b2) -> bf16 LDS, packed 8B writes ----
#pragma unroll
    for (int fn = 0; fn < 4; ++fn) {
        f32x4 b2v = *(const f32x4*)(b2 + wn * 64 + fn * 16 + kg * 4);
#pragma unroll
        for (int fm = 0; fm < 8; ++fm) {
            int prow = fm * 16 + l15;
            u16x4 pv;
#pragma unroll
            for (int r = 0; r < 4; ++r)
                pv[r] = f2bfu(fmaxf(acc[fn][fm][r] + b2v[r], 0.f));
            int byte = (prow << 9) + ((wn * 64 + fn * 16 + kg * 4) << 1);
            byte ^= (prow & 7) << 4;
            *(u16x4*)((char*)smem + byte) = pv;
        }
    }
    __syncthreads();

    // ---- GEMM2: h3^T = w3 x h2^T ----
#pragma unroll
    for (int fn = 0; fn < 4; ++fn)
#pragma unroll
        for (int fm = 0; fm < 8; ++fm) acc[fn][fm] = f32x4{0.f, 0.f, 0.f, 0.f};
    GEMM_DBUF(w3i)

    // ---- masked col-sum + 16-lane reduce + store to part ----
    float s[4][4] = {};
#pragma unroll
    for (int fm = 0; fm < 8; ++fm) {
        int pr = fm * 16 + l15;
        int ki = k0 + (pr >> 3);
        int li = l0 + (pr & 7);
        float vm = (ki < kHW && li < kHW) ? 1.f : 0.f;
#pragma unroll
        for (int fn = 0; fn < 4; ++fn) {
            f32x4 b3v = *(const f32x4*)(b3 + wn * 64 + fn * 16 + kg * 4);
#pragma unroll
            for (int r = 0; r < 4; ++r)
                s[fn][r] += vm * fmaxf(acc[fn][fm][r] + b3v[r], 0.f);
        }
    }
#pragma unroll
    for (int fn = 0; fn < 4; ++fn)
#pragma unroll
        for (int r = 0; r < 4; ++r) {
            s[fn][r] += __shfl_xor(s[fn][r], 1);
            s[fn][r] += __shfl_xor(s[fn][r], 2);
            s[fn][r] += __shfl_xor(s[fn][r], 4);
            s[fn][r] += __shfl_xor(s[fn][r], 8);
        }
    if (l15 == 0) {
        int chunkid = (b * kKC + kc) * kLC + lc;
        float* pp = part + chunkid * 256 + wn * 64 + kg * 4;
#pragma unroll
        for (int fn = 0; fn < 4; ++fn)
            *(f32x4*)(pp + fn * 16) = f32x4{s[fn][0], s[fn][1], s[fn][2], s[fn][3]};
    }
}

// ---------------- final reduce: 64 blocks (b x 8 ch-octants) ----------------
__global__ __launch_bounds__(256)
void k_reduce(const float* __restrict__ part, float* __restrict__ out) {
    __shared__ float red[256];
    int b = blockIdx.x >> 3, s = blockIdx.x & 7;
    int c32 = threadIdx.x & 31, stripe = threadIdx.x >> 5;
    int c = s * 32 + c32;
    const float* p = part + b * kChunks * 256 + c;
    float sum = 0.f;
    for (int j = stripe; j < kChunks; j += 8) sum += p[j * 256];
    red[threadIdx.x] = sum;
    __syncthreads();
    if (threadIdx.x < 32) {
        float t = 0.f;
#pragma unroll
        for (int st = 0; st < 8; ++st) t += red[st * 32 + c32];
        out[b * 256 + c] = t;
    }
}

extern "C" void kernel_launch(void* const* d_in, const int* in_sizes, int n_in,
                              void* d_out, int out_size, void* d_ws, size_t ws_size,
                              hipStream_t stream) {
    const float* im = (const float*)d_in[0];
    const float* pw = (const float*)d_in[3];
    const float* pb = (const float*)d_in[4];
    const float* w1 = (const float*)d_in[5];
    const float* b1 = (const float*)d_in[6];
    const float* w2 = (const float*)d_in[7];
    const float* b2 = (const float*)d_in[8];
    const float* w3 = (const float*)d_in[9];
    const float* b3 = (const float*)d_in[10];
    float* out = (float*)d_out;

    float* al  = (float*)d_ws;            // 8*196*256
    float* ak  = al + 8 * 196 * 256;
    u16* pwi  = (u16*)(ak + 8 * 196 * 256);  // [64 k8-blk][256 n][8 k]
    u16* w1li = pwi + 512 * 256;             // [32 k8-blk][256 n][8 k]
    u16* w1ki = w1li + 256 * 256;
    u16* w2i  = w1ki + 256 * 256;
    u16* w3i  = w2i + 256 * 256;
    float* part = (float*)(w3i + 256 * 256); // [8*325][256] = 2.66 MB

    hipLaunchKernelGGL(k_prep, dim3(1536), dim3(256), 0, stream,
                       pw, pwi, w1, w1li, w1ki, w2, w2i, w3, w3i);
    hipLaunchKernelGGL(k_xa3, dim3(14, 8), dim3(256), 0, stream,
                       im, pwi, pb, w1li, w1ki, al, ak);
    hipLaunchKernelGGL(k_main11, dim3(kLC, kKC, 8), dim3(256), 0, stream,
                       ak, al, b1, w2i, b2, w3i, b3, part);
    hipLaunchKernelGGL(k_reduce, dim3(64), dim3(256), 0, stream, part, out);
}

// Round 15
// 124.315 us; speedup vs baseline: 2.7612x; 1.0386x over previous
//
#include <hip/hip_runtime.h>
#include <hip/hip_bf16.h>

typedef unsigned short u16;
typedef float  f32x4  __attribute__((ext_vector_type(4)));
typedef __bf16 bf16x8 __attribute__((ext_vector_type(8)));
typedef unsigned short u16x8 __attribute__((ext_vector_type(8)));
typedef unsigned short u16x4 __attribute__((ext_vector_type(4)));

__device__ __forceinline__ u16 f2bfu(float f) {
    __hip_bfloat16 h = __float2bfloat16(f);
    return __builtin_bit_cast(unsigned short, h);
}

constexpr int kHW = 196;   // 14*14
constexpr int kKC = 13;    // ceil(196/16) k-chunks (16 k rows per tile)
constexpr int kLC = 25;    // ceil(196/8)  l-chunks (8 l rows per tile)
constexpr int kChunks = kKC * kLC;  // 325 per batch

// ---------------- prep: interleave weights [k>>3][n][k8] bf16 ----------------
__global__ __launch_bounds__(256)
void k_prep(const float* __restrict__ pw, u16* __restrict__ pwi,
            const float* __restrict__ w1, u16* __restrict__ w1li, u16* __restrict__ w1ki,
            const float* __restrict__ w2, u16* __restrict__ w2i,
            const float* __restrict__ w3, u16* __restrict__ w3i) {
    int id = blockIdx.x;
    int n = threadIdx.x;
    if (id < 512) {
        int k = id;
        pwi[((k >> 3) << 11) + (n << 3) + (k & 7)] = f2bfu(pw[n * 512 + k]);
    } else {
        int k = (id - 512) & 255;
        int idx = ((k >> 3) << 11) + (n << 3) + (k & 7);
        if (id < 768)       w1li[idx] = f2bfu(w1[k * 256 + n]);
        else if (id < 1024) w1ki[idx] = f2bfu(w1[(k + 256) * 256 + n]);
        else if (id < 1280) w2i[idx]  = f2bfu(w2[k * 256 + n]);
        else                w3i[idx]  = f2bfu(w3[k * 256 + n]);
    }
}

// ---------------- MFMA prologue: xf then al/ak. grid (14, 8), 256 thr ----------------
__global__ __launch_bounds__(256, 2)
void k_xa3(const float* __restrict__ im, const u16* __restrict__ pwi,
           const float* __restrict__ pb, const u16* __restrict__ w1li,
           const u16* __restrict__ w1ki, float* __restrict__ al,
           float* __restrict__ ak) {
    __shared__ u16 imT[16 * 512];   // [p][i] bf16, swizzled rows (1KB), 16KB
    __shared__ u16 xfs[16 * 256];   // [p][c] bf16, swizzled rows (512B), 8KB
    const int tid = threadIdx.x;
    const int b = blockIdx.y;
    const int p0 = blockIdx.x * 14;

    {
        int t4 = tid & 3;
        int ibase = tid >> 2;
#pragma unroll
        for (int it = 0; it < 8; ++it) {
            int i = it * 64 + ibase;
            const float* src = im + (b * 512 + i) * kHW;
#pragma unroll
            for (int j = 0; j < 4; ++j) {
                int prow = t4 * 4 + j;
                int p = p0 + prow; if (p > 195) p = 195;
                int byte = (prow << 10) + (i << 1);
                byte ^= (prow & 7) << 4;
                *(u16*)((char*)imT + byte) = f2bfu(src[p]);
            }
        }
    }
    __syncthreads();

    const int lane = tid & 63;
    const int wn = tid >> 6;
    const int l15 = lane & 15;
    const int kg = lane >> 4;
    const int wbase = (wn * 64 + l15) << 3;

    f32x4 acc[4];
#pragma unroll
    for (int fn = 0; fn < 4; ++fn) acc[fn] = f32x4{0.f, 0.f, 0.f, 0.f};
    for (int kk = 0; kk < 16; ++kk) {
        int kb = kk * 32 + kg * 8;
        int byte = (l15 << 10) + (kb << 1);
        byte ^= (l15 & 7) << 4;
        bf16x8 hb = __builtin_bit_cast(bf16x8, *(const u16x8*)((const char*)imT + byte));
        const u16* wp = pwi + ((((kk << 2) + kg) << 11) + wbase);
#pragma unroll
        for (int fn = 0; fn < 4; ++fn) {
            bf16x8 aw = __builtin_bit_cast(bf16x8, *(const u16x8*)(wp + (fn << 7)));
            acc[fn] = __builtin_amdgcn_mfma_f32_16x16x32_bf16(aw, hb, acc[fn], 0, 0, 0);
        }
    }
#pragma unroll
    for (int fn = 0; fn < 4; ++fn) {
        f32x4 pbv = *(const f32x4*)(pb + wn * 64 + fn * 16 + kg * 4);
        u16x4 pv;
#pragma unroll
        for (int r = 0; r < 4; ++r) pv[r] = f2bfu(acc[fn][r] + pbv[r]);
        int byte = (l15 << 9) + ((wn * 64 + fn * 16 + kg * 4) << 1);
        byte ^= (l15 & 7) << 4;
        *(u16x4*)((char*)xfs + byte) = pv;
    }
    __syncthreads();

    const int p = p0 + l15;
    const bool valid = (l15 < 14) && (p < kHW);
#pragma unroll
    for (int sel = 0; sel < 2; ++sel) {
        const u16* wsrc = sel ? w1ki : w1li;
        f32x4 a2[4];
#pragma unroll
        for (int fn = 0; fn < 4; ++fn) a2[fn] = f32x4{0.f, 0.f, 0.f, 0.f};
        for (int kk = 0; kk < 8; ++kk) {
            int kb = kk * 32 + kg * 8;
            int byte = (l15 << 9) + (kb << 1);
            byte ^= (l15 & 7) << 4;
            bf16x8 hb = __builtin_bit_cast(bf16x8, *(const u16x8*)((const char*)xfs + byte));
            const u16* wp = wsrc + ((((kk << 2) + kg) << 11) + wbase);
#pragma unroll
            for (int fn = 0; fn < 4; ++fn) {
                bf16x8 aw = __builtin_bit_cast(bf16x8, *(const u16x8*)(wp + (fn << 7)));
                a2[fn] = __builtin_amdgcn_mfma_f32_16x16x32_bf16(aw, hb, a2[fn], 0, 0, 0);
            }
        }
        if (valid) {
            float* dst = (sel ? ak : al) + ((b * kHW + p) << 8) + wn * 64 + kg * 4;
#pragma unroll
            for (int fn = 0; fn < 4; ++fn) *(f32x4*)(dst + fn * 16) = a2[fn];
        }
    }
}

// ---------------- main v12 = v10 (R12-exact) + s_setprio around MFMA loops ---------
// grid (25 lc, 13 kc, 8 b) = 2600 blocks, block 256 (4 waves; wave = ch quarter).
// Tile: (16 k x 8 l) = 128 pairs x 256 ch. acc[4][8]=128 AGPR; aw[4] preloaded,
// hb streamed one-at-a-time -> no spill at (256,2).
__global__ __launch_bounds__(256, 2)
void k_main12(const float* __restrict__ ak, const float* __restrict__ al,
              const float* __restrict__ b1, const u16* __restrict__ w2i,
              const float* __restrict__ b2, const u16* __restrict__ w3i,
              const float* __restrict__ b3, float* __restrict__ part) {
    __shared__ u16 smem[128 * 256];  // 64 KB: h1, then h2 in-place
    const int tid = threadIdx.x;
    const int lc = blockIdx.x, kc = blockIdx.y, b = blockIdx.z;
    const int k0 = kc * 16, l0 = lc * 8;

    // ---- build h1 = relu(ak[k]+al[l]+b1) -> bf16 LDS [pair][ch] ----
    {
        const int cc = tid & 31;
        f32x4 c0v = *(const f32x4*)(b1 + (cc << 3));
        f32x4 c1v = *(const f32x4*)(b1 + (cc << 3) + 4);
#pragma unroll
        for (int it = 0; it < 16; ++it) {
            int row = (it * 256 + tid) >> 5;  // 0..127 = (ki-k0)*8 + (li-l0)
            int ki = k0 + (row >> 3); if (ki > 195) ki = 195;
            int li = l0 + (row & 7);  if (li > 195) li = 195;
            const float* akp = ak + ((b * kHW + ki) << 8) + (cc << 3);
            const float* alp = al + ((b * kHW + li) << 8) + (cc << 3);
            f32x4 k0v = *(const f32x4*)akp;
            f32x4 k1v = *(const f32x4*)(akp + 4);
            f32x4 l0v = *(const f32x4*)alp;
            f32x4 l1v = *(const f32x4*)(alp + 4);
            u16x8 v;
#pragma unroll
            for (int j = 0; j < 4; ++j) {
                v[j]     = f2bfu(fmaxf(k0v[j] + l0v[j] + c0v[j], 0.f));
                v[4 + j] = f2bfu(fmaxf(k1v[j] + l1v[j] + c1v[j], 0.f));
            }
            int byte = (row << 9) + (cc << 4);
            byte ^= (row & 7) << 4;
            *(u16x8*)((char*)smem + byte) = v;
        }
    }
    __syncthreads();

    const int lane = tid & 63;
    const int wn = tid >> 6;   // wave = ch quarter 0..3
    const int l15 = lane & 15;
    const int kg = lane >> 4;  // 0..3
    const int wbase = (wn * 64 + l15) << 3;

    f32x4 acc[4][8];  // [fn ch-frag][fm pair-frag], reused for both GEMMs

    // ---- GEMM1: h2^T = w2 x h1^T (aw preloaded, hb streamed) ----
#pragma unroll
    for (int fn = 0; fn < 4; ++fn)
#pragma unroll
        for (int fm = 0; fm < 8; ++fm) acc[fn][fm] = f32x4{0.f, 0.f, 0.f, 0.f};
    __builtin_amdgcn_s_setprio(1);
    for (int kk = 0; kk < 8; ++kk) {
        int kb = kk * 32 + kg * 8;
        const u16* wp = w2i + ((((kk << 2) + kg) << 11) + wbase);
        bf16x8 aw[4];
#pragma unroll
        for (int fn = 0; fn < 4; ++fn)
            aw[fn] = __builtin_bit_cast(bf16x8, *(const u16x8*)(wp + (fn << 7)));
#pragma unroll
        for (int fm = 0; fm < 8; ++fm) {
            int row = fm * 16 + l15;
            int byte = (row << 9) + (kb << 1);
            byte ^= (row & 7) << 4;
            bf16x8 hb = __builtin_bit_cast(bf16x8, *(const u16x8*)((const char*)smem + byte));
#pragma unroll
            for (int fn = 0; fn < 4; ++fn)
                acc[fn][fm] = __builtin_amdgcn_mfma_f32_16x16x32_bf16(aw[fn], hb, acc[fn][fm], 0, 0, 0);
        }
    }
    __builtin_amdgcn_s_setprio(0);
    __syncthreads();

    // ---- epilogue: h2 = relu(D1 + b2) -> bf16 LDS, packed 8B writes ----
#pragma unroll
    for (int fn = 0; fn < 4; ++fn) {
        f32x4 b2v = *(const f32x4*)(b2 + wn * 64 + fn * 16 + kg * 4);
#pragma unroll
        for (int fm = 0; fm < 8; ++fm) {
            int prow = fm * 16 + l15;
            u16x4 pv;
#pragma unroll
            for (int r = 0; r < 4; ++r)
                pv[r] = f2bfu(fmaxf(acc[fn][fm][r] + b2v[r], 0.f));
            int byte = (prow << 9) + ((wn * 64 + fn * 16 + kg * 4) << 1);
            byte ^= (prow & 7) << 4;
            *(u16x4*)((char*)smem + byte) = pv;
        }
    }
    __syncthreads();

    // ---- GEMM2: h3^T = w3 x h2^T ----
#pragma unroll
    for (int fn = 0; fn < 4; ++fn)
#pragma unroll
        for (int fm = 0; fm < 8; ++fm) acc[fn][fm] = f32x4{0.f, 0.f, 0.f, 0.f};
    __builtin_amdgcn_s_setprio(1);
    for (int kk = 0; kk < 8; ++kk) {
        int kb = kk * 32 + kg * 8;
        const u16* wp = w3i + ((((kk << 2) + kg) << 11) + wbase);
        bf16x8 aw[4];
#pragma unroll
        for (int fn = 0; fn < 4; ++fn)
            aw[fn] = __builtin_bit_cast(bf16x8, *(const u16x8*)(wp + (fn << 7)));
#pragma unroll
        for (int fm = 0; fm < 8; ++fm) {
            int row = fm * 16 + l15;
            int byte = (row << 9) + (kb << 1);
            byte ^= (row & 7) << 4;
            bf16x8 hb = __builtin_bit_cast(bf16x8, *(const u16x8*)((const char*)smem + byte));
#pragma unroll
            for (int fn = 0; fn < 4; ++fn)
                acc[fn][fm] = __builtin_amdgcn_mfma_f32_16x16x32_bf16(aw[fn], hb, acc[fn][fm], 0, 0, 0);
        }
    }
    __builtin_amdgcn_s_setprio(0);

    // ---- masked col-sum + 16-lane reduce + store to part ----
    float s[4][4] = {};
#pragma unroll
    for (int fm = 0; fm < 8; ++fm) {
        int pr = fm * 16 + l15;
        int ki = k0 + (pr >> 3);
        int li = l0 + (pr & 7);
        float vm = (ki < kHW && li < kHW) ? 1.f : 0.f;
#pragma unroll
        for (int fn = 0; fn < 4; ++fn) {
            f32x4 b3v = *(const f32x4*)(b3 + wn * 64 + fn * 16 + kg * 4);
#pragma unroll
            for (int r = 0; r < 4; ++r)
                s[fn][r] += vm * fmaxf(acc[fn][fm][r] + b3v[r], 0.f);
        }
    }
#pragma unroll
    for (int fn = 0; fn < 4; ++fn)
#pragma unroll
        for (int r = 0; r < 4; ++r) {
            s[fn][r] += __shfl_xor(s[fn][r], 1);
            s[fn][r] += __shfl_xor(s[fn][r], 2);
            s[fn][r] += __shfl_xor(s[fn][r], 4);
            s[fn][r] += __shfl_xor(s[fn][r], 8);
        }
    if (l15 == 0) {
        int chunkid = (b * kKC + kc) * kLC + lc;
        float* pp = part + chunkid * 256 + wn * 64 + kg * 4;
#pragma unroll
        for (int fn = 0; fn < 4; ++fn)
            *(f32x4*)(pp + fn * 16) = f32x4{s[fn][0], s[fn][1], s[fn][2], s[fn][3]};
    }
}

// ---------------- final reduce: 64 blocks (b x 8 ch-octants) ----------------
__global__ __launch_bounds__(256)
void k_reduce(const float* __restrict__ part, float* __restrict__ out) {
    __shared__ float red[256];
    int b = blockIdx.x >> 3, s = blockIdx.x & 7;
    int c32 = threadIdx.x & 31, stripe = threadIdx.x >> 5;
    int c = s * 32 + c32;
    const float* p = part + b * kChunks * 256 + c;
    float sum = 0.f;
    for (int j = stripe; j < kChunks; j += 8) sum += p[j * 256];
    red[threadIdx.x] = sum;
    __syncthreads();
    if (threadIdx.x < 32) {
        float t = 0.f;
#pragma unroll
        for (int st = 0; st < 8; ++st) t += red[st * 32 + c32];
        out[b * 256 + c] = t;
    }
}

extern "C" void kernel_launch(void* const* d_in, const int* in_sizes, int n_in,
                              void* d_out, int out_size, void* d_ws, size_t ws_size,
                              hipStream_t stream) {
    const float* im = (const float*)d_in[0];
    const float* pw = (const float*)d_in[3];
    const float* pb = (const float*)d_in[4];
    const float* w1 = (const float*)d_in[5];
    const float* b1 = (const float*)d_in[6];
    const float* w2 = (const float*)d_in[7];
    const float* b2 = (const float*)d_in[8];
    const float* w3 = (const float*)d_in[9];
    const float* b3 = (const float*)d_in[10];
    float* out = (float*)d_out;

    float* al  = (float*)d_ws;            // 8*196*256
    float* ak  = al + 8 * 196 * 256;
    u16* pwi  = (u16*)(ak + 8 * 196 * 256);  // [64 k8-blk][256 n][8 k]
    u16* w1li = pwi + 512 * 256;             // [32 k8-blk][256 n][8 k]
    u16* w1ki = w1li + 256 * 256;
    u16* w2i  = w1ki + 256 * 256;
    u16* w3i  = w2i + 256 * 256;
    float* part = (float*)(w3i + 256 * 256); // [8*325][256] = 2.66 MB

    hipLaunchKernelGGL(k_prep, dim3(1536), dim3(256), 0, stream,
                       pw, pwi, w1, w1li, w1ki, w2, w2i, w3, w3i);
    hipLaunchKernelGGL(k_xa3, dim3(14, 8), dim3(256), 0, stream,
                       im, pwi, pb, w1li, w1ki, al, ak);
    hipLaunchKernelGGL(k_main12, dim3(kLC, kKC, 8), dim3(256), 0, stream,
                       ak, al, b1, w2i, b2, w3i, b3, part);
    hipLaunchKernelGGL(k_reduce, dim3(64), dim3(256), 0, stream, part, out);
}